// Round 6
// baseline (3322.861 us; speedup 1.0000x reference)
//
#include <hip/hip_runtime.h>
#include <hip/hip_bf16.h>

#define CI_ 64
#define CO_ 128
#define NPIX 4096
#define CQ_ 16
#define QR 2
#define EPS_ 1e-5f

// a = relu(bn2(Wa @ x + ba))
__global__ __launch_bounds__(256) void z_proj_a(
    const float* __restrict__ x, const float* __restrict__ Wa, const float* __restrict__ ba,
    const float* __restrict__ g, const float* __restrict__ bb,
    const float* __restrict__ m, const float* __restrict__ v, float* __restrict__ a)
{
    int i = blockIdx.x * 256 + threadIdx.x;
    int n = i & (NPIX - 1);
    int co = (i >> 12) & (CO_ - 1);
    int b = i >> 19;
    const float* xp = x + b * CI_ * NPIX + n;
    const float* wp = Wa + co * CI_;
    float acc = ba[co];
#pragma unroll 8
    for (int ci = 0; ci < CI_; ++ci) acc += wp[ci] * xp[ci * NPIX];
    float y = (acc - m[co]) * rsqrtf(v[co] + EPS_) * g[co] + bb[co];
    a[i] = fmaxf(y, 0.f);
}

// local = relu(bn1(conv3x3(x) + b3))
__global__ __launch_bounds__(256) void z_conv3(
    const float* __restrict__ x, const float* __restrict__ W3, const float* __restrict__ b3,
    const float* __restrict__ g, const float* __restrict__ bb,
    const float* __restrict__ m, const float* __restrict__ v, float* __restrict__ local)
{
    int i = blockIdx.x * 256 + threadIdx.x;
    int w = i & 63;
    int h = (i >> 6) & 63;
    int co = (i >> 12) & (CO_ - 1);
    int b = i >> 19;
    float acc = b3[co];
    for (int ci = 0; ci < CI_; ++ci) {
        const float* xp = x + (b * CI_ + ci) * NPIX;
        const float* wp = W3 + (co * CI_ + ci) * 9;
#pragma unroll
        for (int kh = 0; kh < 3; ++kh) {
            int hh = h + kh - 1;
            if ((unsigned)hh >= 64u) continue;
#pragma unroll
            for (int kw = 0; kw < 3; ++kw) {
                int ww = w + kw - 1;
                if ((unsigned)ww >= 64u) continue;
                acc += wp[kh * 3 + kw] * xp[hh * 64 + ww];
            }
        }
    }
    float y = (acc - m[co]) * rsqrtf(v[co] + EPS_) * g[co] + bb[co];
    local[i] = fmaxf(y, 0.f);
}

// q/k projection (Cout=16)
__global__ __launch_bounds__(256) void z_projqk(
    const float* __restrict__ a, const float* __restrict__ W, const float* __restrict__ bias,
    float* __restrict__ out)
{
    int i = blockIdx.x * 256 + threadIdx.x;
    int n = i & (NPIX - 1);
    int c = (i >> 12) & (CQ_ - 1);
    int b = i >> 16;
    const float* ap = a + b * CO_ * NPIX + n;
    const float* wp = W + c * CO_;
    float acc = bias[c];
#pragma unroll 8
    for (int t = 0; t < CO_; ++t) acc += wp[t] * ap[t * NPIX];
    out[i] = acc;
}

// vT[b][n][c] = Wv[c,:] . a[b,:,n] + bv[c]
__global__ __launch_bounds__(256) void z_projv(
    const float* __restrict__ a, const float* __restrict__ Wv, const float* __restrict__ bv,
    float* __restrict__ vT)
{
    int i = blockIdx.x * 256 + threadIdx.x;
    int c = i & (CO_ - 1);
    int n = (i >> 7) & (NPIX - 1);
    int b = i >> 19;
    const float* ap = a + b * CO_ * NPIX + n;
    const float* wp = Wv + c * CO_;
    float acc = bv[c];
#pragma unroll 8
    for (int t = 0; t < CO_; ++t) acc += wp[t] * ap[t * NPIX];
    vT[i] = acc;
}

// attention, QR=2 query rows per block. LDS = 2*4096*4 = 32KB (+1KB red).
// attn[idx] = gam * o + a[idx]
__global__ __launch_bounds__(256) void z_attn(
    const float* __restrict__ q, const float* __restrict__ k, const float* __restrict__ vT,
    const float* __restrict__ a, const float* __restrict__ gamp, float* __restrict__ attn)
{
    __shared__ float s[QR][NPIX];      // 32 KB
    __shared__ float qs[QR][CQ_];
    __shared__ float red[256];
    int tid = threadIdx.x;
    int b = blockIdx.x >> 11;          // 2048 blocks per batch
    int n0 = (blockIdx.x & 2047) * QR;

    if (tid < QR * CQ_) {
        int qi = tid >> 4, c = tid & 15;
        qs[qi][c] = q[(b * CQ_ + c) * NPIX + n0 + qi];
    }
    __syncthreads();

    for (int mm = tid; mm < NPIX; mm += 256) {
        float kv[CQ_];
#pragma unroll
        for (int c = 0; c < CQ_; ++c) kv[c] = k[(b * CQ_ + c) * NPIX + mm];
#pragma unroll
        for (int qi = 0; qi < QR; ++qi) {
            float acc = 0.f;
#pragma unroll
            for (int c = 0; c < CQ_; ++c) acc += qs[qi][c] * kv[c];
            s[qi][mm] = acc;
        }
    }
    __syncthreads();

    float sinv[QR];
    for (int qi = 0; qi < QR; ++qi) {
        float mx = -1e30f;
        for (int mm = tid; mm < NPIX; mm += 256) mx = fmaxf(mx, s[qi][mm]);
        red[tid] = mx;
        __syncthreads();
        for (int st = 128; st > 0; st >>= 1) {
            if (tid < st) red[tid] = fmaxf(red[tid], red[tid + st]);
            __syncthreads();
        }
        float rowmax = red[0];
        __syncthreads();
        float sum = 0.f;
        for (int mm = tid; mm < NPIX; mm += 256) {
            float p = __expf(s[qi][mm] - rowmax);
            s[qi][mm] = p;
            sum += p;
        }
        red[tid] = sum;
        __syncthreads();
        for (int st = 128; st > 0; st >>= 1) {
            if (tid < st) red[tid] += red[tid + st];
            __syncthreads();
        }
        sinv[qi] = 1.f / red[0];
        __syncthreads();
    }

    // PV: 256 threads = 128 channels x 2 queries
    int c = tid & (CO_ - 1);
    int qi = tid >> 7;                  // 0 or 1
    float acc = 0.f;
    const float* vp = vT + b * NPIX * CO_ + c;
#pragma unroll 4
    for (int mm = 0; mm < NPIX; ++mm) acc += s[qi][mm] * vp[mm * CO_];
    float gam = gamp[0];
    int idx = (b * CO_ + c) * NPIX + n0 + qi;
    attn[idx] = gam * (acc * sinv[qi]) + a[idx];
}

// gate + fuse
__global__ __launch_bounds__(256) void z_gate(
    const float* __restrict__ local, const float* __restrict__ attn,
    const float* __restrict__ Wg, const float* __restrict__ bg,
    const float* __restrict__ g, const float* __restrict__ bb,
    const float* __restrict__ m, const float* __restrict__ v, float* __restrict__ fused)
{
    int i = blockIdx.x * 256 + threadIdx.x;
    int n = i & (NPIX - 1);
    int co = (i >> 12) & (CO_ - 1);
    int b = i >> 19;
    const float* lp = local + b * CO_ * NPIX + n;
    const float* ap = attn + b * CO_ * NPIX + n;
    const float* wp = Wg + co * 2 * CO_;
    float acc = bg[co];
#pragma unroll 8
    for (int c = 0; c < CO_; ++c) acc += wp[c] * lp[c * NPIX];
#pragma unroll 8
    for (int c = 0; c < CO_; ++c) acc += wp[CO_ + c] * ap[c * NPIX];
    float z = (acc - m[co]) * rsqrtf(v[co] + EPS_) * g[co] + bb[co];
    float gate = 1.f / (1.f + __expf(-z));
    fused[i] = gate * lp[co * NPIX] + (1.f - gate) * ap[co * NPIX];
}

// final: relu(bn4(Wf @ [fused;local;attn])) + rs*(Wr @ x)  -> FLOAT32 out
__global__ __launch_bounds__(256) void z_out(
    const float* __restrict__ fused, const float* __restrict__ local, const float* __restrict__ attn,
    const float* __restrict__ x, const float* __restrict__ Wf, const float* __restrict__ bfb,
    const float* __restrict__ g, const float* __restrict__ bb,
    const float* __restrict__ m, const float* __restrict__ v,
    const float* __restrict__ Wr, const float* __restrict__ rsp, float* __restrict__ out)
{
    int i = blockIdx.x * 256 + threadIdx.x;
    int n = i & (NPIX - 1);
    int co = (i >> 12) & (CO_ - 1);
    int b = i >> 19;
    const float* fp = fused + b * CO_ * NPIX + n;
    const float* lp = local + b * CO_ * NPIX + n;
    const float* ap = attn + b * CO_ * NPIX + n;
    const float* wp = Wf + co * 3 * CO_;
    float acc = bfb[co];
#pragma unroll 8
    for (int c = 0; c < CO_; ++c) acc += wp[c] * fp[c * NPIX];
#pragma unroll 8
    for (int c = 0; c < CO_; ++c) acc += wp[CO_ + c] * lp[c * NPIX];
#pragma unroll 8
    for (int c = 0; c < CO_; ++c) acc += wp[2 * CO_ + c] * ap[c * NPIX];
    float z = (acc - m[co]) * rsqrtf(v[co] + EPS_) * g[co] + bb[co];
    float r = 0.f;
    const float* xp = x + b * CI_ * NPIX + n;
    const float* wr = Wr + co * CI_;
#pragma unroll 8
    for (int ci = 0; ci < CI_; ++ci) r += wr[ci] * xp[ci * NPIX];
    out[i] = fmaxf(z, 0.f) + rsp[0] * r;
}

extern "C" void kernel_launch(void* const* d_in, const int* in_sizes, int n_in,
                              void* d_out, int out_size, void* d_ws, size_t ws_size,
                              hipStream_t stream) {
    const float* x   = (const float*)d_in[0];
    const float* W3  = (const float*)d_in[1];
    const float* b3  = (const float*)d_in[2];
    const float* g1  = (const float*)d_in[3];
    const float* b1  = (const float*)d_in[4];
    const float* m1  = (const float*)d_in[5];
    const float* v1  = (const float*)d_in[6];
    const float* Wa  = (const float*)d_in[7];
    const float* ba  = (const float*)d_in[8];
    const float* g2  = (const float*)d_in[9];
    const float* b2  = (const float*)d_in[10];
    const float* m2  = (const float*)d_in[11];
    const float* v2  = (const float*)d_in[12];
    const float* Wq  = (const float*)d_in[13];
    const float* bq  = (const float*)d_in[14];
    const float* Wk  = (const float*)d_in[15];
    const float* bk  = (const float*)d_in[16];
    const float* Wv  = (const float*)d_in[17];
    const float* bv  = (const float*)d_in[18];
    const float* gam = (const float*)d_in[19];
    const float* Wg  = (const float*)d_in[20];
    const float* bg  = (const float*)d_in[21];
    const float* g3  = (const float*)d_in[22];
    const float* b3n = (const float*)d_in[23];
    const float* m3  = (const float*)d_in[24];
    const float* v3  = (const float*)d_in[25];
    const float* Wf  = (const float*)d_in[26];
    const float* bfb = (const float*)d_in[27];
    const float* g4  = (const float*)d_in[28];
    const float* b4  = (const float*)d_in[29];
    const float* m4  = (const float*)d_in[30];
    const float* v4  = (const float*)d_in[31];
    const float* Wr  = (const float*)d_in[32];
    const float* rs  = (const float*)d_in[33];

    float* ws    = (float*)d_ws;
    float* a_    = ws;                  // [0, 2M) floats
    float* local = ws + 2097152;        // [2M, 4M)
    float* attn  = ws + 4194304;        // [4M, 6M)
    float* vT    = ws + 6291456;        // [6M, 8M); fused aliases (vT dead after z_attn)
    float* q     = ws + 8388608;        // 262,144
    float* kk    = ws + 8650752;        // 262,144  -> total 34 MiB
    float* fused = vT;

    float* out = (float*)d_out;

    z_proj_a<<<8192, 256, 0, stream>>>(x, Wa, ba, g2, b2, m2, v2, a_);
    z_projqk<<<1024, 256, 0, stream>>>(a_, Wq, bq, q);
    z_projqk<<<1024, 256, 0, stream>>>(a_, Wk, bk, kk);
    z_projv<<<8192, 256, 0, stream>>>(a_, Wv, bv, vT);
    z_attn<<<8192, 256, 0, stream>>>(q, kk, vT, a_, gam, attn);
    z_conv3<<<8192, 256, 0, stream>>>(x, W3, b3, g1, b1, m1, v1, local);
    z_gate<<<8192, 256, 0, stream>>>(local, attn, Wg, bg, g3, b3n, m3, v3, fused);
    z_out<<<8192, 256, 0, stream>>>(fused, local, attn, x, Wf, bfb, g4, b4, m4, v4, Wr, rs, out);
}

// Round 7
// 1846.508 us; speedup vs baseline: 1.7995x; 1.7995x over previous
//
#include <hip/hip_runtime.h>
#include <hip/hip_bf16.h>

#define CI_ 64
#define CO_ 128
#define NPIX 4096
#define CQ_ 16
#define QT 16
#define MT 256
#define EPS_ 1e-5f

// a = relu(bn2(Wa @ x + ba)), 4 outputs per thread along n
__global__ __launch_bounds__(256) void z_proj_a4(
    const float* __restrict__ x, const float* __restrict__ Wa, const float* __restrict__ ba,
    const float* __restrict__ g, const float* __restrict__ bb,
    const float* __restrict__ m, const float* __restrict__ v, float* __restrict__ a)
{
    int i = blockIdx.x * 256 + threadIdx.x;   // B*CO*1024
    int n4 = (i & 1023) * 4;
    int co = (i >> 10) & (CO_ - 1);
    int b = i >> 17;
    const float4* xp = (const float4*)(x + (size_t)b * CI_ * NPIX + n4);
    const float* wp = Wa + co * CI_;
    float4 acc;
    acc.x = acc.y = acc.z = acc.w = ba[co];
#pragma unroll 8
    for (int ci = 0; ci < CI_; ++ci) {
        float4 xv = xp[ci * (NPIX / 4)];
        float w = wp[ci];
        acc.x += w * xv.x; acc.y += w * xv.y; acc.z += w * xv.z; acc.w += w * xv.w;
    }
    float sc = rsqrtf(v[co] + EPS_) * g[co];
    float sh = bb[co] - m[co] * sc;
    float4 r;
    r.x = fmaxf(acc.x * sc + sh, 0.f);
    r.y = fmaxf(acc.y * sc + sh, 0.f);
    r.z = fmaxf(acc.z * sc + sh, 0.f);
    r.w = fmaxf(acc.w * sc + sh, 0.f);
    *(float4*)(a + ((size_t)b * CO_ + co) * NPIX + n4) = r;
}

// local = relu(bn1(conv3x3(x) + b3)), interior fast path
__global__ __launch_bounds__(256) void z_conv3(
    const float* __restrict__ x, const float* __restrict__ W3, const float* __restrict__ b3,
    const float* __restrict__ g, const float* __restrict__ bb,
    const float* __restrict__ m, const float* __restrict__ v, float* __restrict__ local)
{
    int i = blockIdx.x * 256 + threadIdx.x;
    int w = i & 63;
    int h = (i >> 6) & 63;
    int co = (i >> 12) & (CO_ - 1);
    int b = i >> 19;
    float acc = b3[co];
    if (h >= 1 && h <= 62 && w >= 1 && w <= 62) {
        for (int ci = 0; ci < CI_; ++ci) {
            const float* xp = x + ((size_t)b * CI_ + ci) * NPIX + (h - 1) * 64 + (w - 1);
            const float* wp = W3 + (co * CI_ + ci) * 9;
#pragma unroll
            for (int kh = 0; kh < 3; ++kh)
#pragma unroll
                for (int kw = 0; kw < 3; ++kw)
                    acc += wp[kh * 3 + kw] * xp[kh * 64 + kw];
        }
    } else {
        for (int ci = 0; ci < CI_; ++ci) {
            const float* xp = x + ((size_t)b * CI_ + ci) * NPIX;
            const float* wp = W3 + (co * CI_ + ci) * 9;
#pragma unroll
            for (int kh = 0; kh < 3; ++kh) {
                int hh = h + kh - 1;
                if ((unsigned)hh >= 64u) continue;
#pragma unroll
                for (int kw = 0; kw < 3; ++kw) {
                    int ww = w + kw - 1;
                    if ((unsigned)ww >= 64u) continue;
                    acc += wp[kh * 3 + kw] * xp[hh * 64 + ww];
                }
            }
        }
    }
    float y = (acc - m[co]) * rsqrtf(v[co] + EPS_) * g[co] + bb[co];
    local[i] = fmaxf(y, 0.f);
}

// q/k projection (Cout=16)
__global__ __launch_bounds__(256) void z_projqk(
    const float* __restrict__ a, const float* __restrict__ W, const float* __restrict__ bias,
    float* __restrict__ out)
{
    int i = blockIdx.x * 256 + threadIdx.x;
    int n = i & (NPIX - 1);
    int c = (i >> 12) & (CQ_ - 1);
    int b = i >> 16;
    const float* ap = a + (size_t)b * CO_ * NPIX + n;
    const float* wp = W + c * CO_;
    float acc = bias[c];
#pragma unroll 8
    for (int t = 0; t < CO_; ++t) acc += wp[t] * ap[t * NPIX];
    out[i] = acc;
}

// vT[b][n][c] = Wv[c,:] . a[b,:,n] + bv[c]
__global__ __launch_bounds__(256) void z_projv(
    const float* __restrict__ a, const float* __restrict__ Wv, const float* __restrict__ bv,
    float* __restrict__ vT)
{
    int i = blockIdx.x * 256 + threadIdx.x;
    int c = i & (CO_ - 1);
    int n = (i >> 7) & (NPIX - 1);
    int b = i >> 19;
    const float* ap = a + (size_t)b * CO_ * NPIX + n;
    const float* wp = Wv + c * CO_;
    float acc = bv[c];
#pragma unroll 8
    for (int t = 0; t < CO_; ++t) acc += wp[t] * ap[t * NPIX];
    vT[i] = acc;
}

// flash attention: QT=16 queries per block, KV tiled by MT=256.
// attn[idx] = gam * o + a[idx]
__global__ __launch_bounds__(256) void z_attn2(
    const float* __restrict__ q, const float* __restrict__ k, const float* __restrict__ vT,
    const float* __restrict__ a, const float* __restrict__ gamp, float* __restrict__ attn)
{
    __shared__ float qs[QT][CQ_];
    __shared__ float p[QT][260];          // MT cols used; pad 260 (16B-aligned rows)
    __shared__ float rmax[QT], rsum[QT], rf[QT], rnm[QT];
    int tid = threadIdx.x;
    int b = blockIdx.x >> 8;              // 256 q-tiles per batch
    int q0 = (blockIdx.x & 255) * QT;

    if (tid < QT * CQ_) {
        int qi = tid >> 4, c = tid & 15;
        qs[qi][c] = q[((size_t)b * CQ_ + c) * NPIX + q0 + qi];
    }
    if (tid < QT) { rmax[tid] = -1e30f; rsum[tid] = 0.f; }

    int c = tid & 127;
    int half = tid >> 7;
    float o[QT];
#pragma unroll
    for (int i = 0; i < QT; ++i) o[i] = 0.f;

    __syncthreads();

    for (int t = 0; t < NPIX / MT; ++t) {
        int m0 = t * MT;
        // ---- phase A: scores for column m = m0 + tid ----
        float kv[CQ_];
#pragma unroll
        for (int cc = 0; cc < CQ_; ++cc) kv[cc] = k[((size_t)b * CQ_ + cc) * NPIX + m0 + tid];
        float s[QT];
#pragma unroll
        for (int qi = 0; qi < QT; ++qi) {
            float acc = 0.f;
#pragma unroll
            for (int cc = 0; cc < CQ_; ++cc) acc += qs[qi][cc] * kv[cc];
            s[qi] = acc;
            p[qi][tid] = acc;
        }
        __syncthreads();
        // row max: group g = tid>>4 owns query g
        {
            int g = tid >> 4, j = tid & 15;
            float mx = -1e30f;
#pragma unroll
            for (int i2 = 0; i2 < 16; ++i2) mx = fmaxf(mx, p[g][j + 16 * i2]);
#pragma unroll
            for (int off = 8; off; off >>= 1) mx = fmaxf(mx, __shfl_xor(mx, off, 16));
            if (j == 0) {
                float om = rmax[g];
                float nm = fmaxf(om, mx);
                rf[g] = __expf(om - nm);
                rnm[g] = nm;
                rmax[g] = nm;
            }
        }
        __syncthreads();
        // exponentiate
#pragma unroll
        for (int qi = 0; qi < QT; ++qi) p[qi][tid] = __expf(s[qi] - rnm[qi]);
        __syncthreads();
        // row sum
        {
            int g = tid >> 4, j = tid & 15;
            float sm = 0.f;
#pragma unroll
            for (int i2 = 0; i2 < 16; ++i2) sm += p[g][j + 16 * i2];
#pragma unroll
            for (int off = 8; off; off >>= 1) sm += __shfl_xor(sm, off, 16);
            if (j == 0) rsum[g] = rsum[g] * rf[g] + sm;
        }
        // ---- phase B: PV for this tile (thread = channel c, m-half) ----
#pragma unroll
        for (int qi = 0; qi < QT; ++qi) o[qi] *= rf[qi];
        const float* vp = vT + (size_t)b * NPIX * CO_ + (size_t)(m0 + half * 128) * CO_ + c;
#pragma unroll 2
        for (int mm = 0; mm < 128; mm += 4) {
            float v0 = vp[(mm + 0) * CO_];
            float v1 = vp[(mm + 1) * CO_];
            float v2 = vp[(mm + 2) * CO_];
            float v3 = vp[(mm + 3) * CO_];
            int mb = half * 128 + mm;
#pragma unroll
            for (int qi = 0; qi < QT; ++qi) {
                float4 pv = *(const float4*)(&p[qi][mb]);
                o[qi] += pv.x * v0 + pv.y * v1 + pv.z * v2 + pv.w * v3;
            }
        }
        __syncthreads();   // p reused next tile
    }

    // combine halves in LDS (reuse p; row stride 132 to avoid bank conflicts)
    float* otile = &p[0][0];
    if (half == 0) {
#pragma unroll
        for (int qi = 0; qi < QT; ++qi) otile[qi * 132 + c] = o[qi];
    }
    __syncthreads();
    if (half == 1) {
#pragma unroll
        for (int qi = 0; qi < QT; ++qi) otile[qi * 132 + c] += o[qi];
    }
    __syncthreads();
    float gam = gamp[0];
    int qi = tid & 15;
    float inv = 1.f / rsum[qi];
#pragma unroll
    for (int j = 0; j < 8; ++j) {
        int cc = (tid >> 4) + 16 * j;
        size_t idx = ((size_t)b * CO_ + cc) * NPIX + q0 + qi;
        attn[idx] = gam * (otile[qi * 132 + cc] * inv) + a[idx];
    }
}

// gate + fuse, 4-wide along n
__global__ __launch_bounds__(256) void z_gate4(
    const float* __restrict__ local, const float* __restrict__ attn,
    const float* __restrict__ Wg, const float* __restrict__ bg,
    const float* __restrict__ g, const float* __restrict__ bb,
    const float* __restrict__ m, const float* __restrict__ v, float* __restrict__ fused)
{
    int i = blockIdx.x * 256 + threadIdx.x;
    int n4 = (i & 1023) * 4;
    int co = (i >> 10) & (CO_ - 1);
    int b = i >> 17;
    const float4* lp = (const float4*)(local + (size_t)b * CO_ * NPIX + n4);
    const float4* ap = (const float4*)(attn + (size_t)b * CO_ * NPIX + n4);
    const float* wp = Wg + co * 2 * CO_;
    float4 acc;
    acc.x = acc.y = acc.z = acc.w = bg[co];
#pragma unroll 8
    for (int cc = 0; cc < CO_; ++cc) {
        float4 lv = lp[cc * (NPIX / 4)];
        float w = wp[cc];
        acc.x += w * lv.x; acc.y += w * lv.y; acc.z += w * lv.z; acc.w += w * lv.w;
    }
#pragma unroll 8
    for (int cc = 0; cc < CO_; ++cc) {
        float4 av = ap[cc * (NPIX / 4)];
        float w = wp[CO_ + cc];
        acc.x += w * av.x; acc.y += w * av.y; acc.z += w * av.z; acc.w += w * av.w;
    }
    float sc = rsqrtf(v[co] + EPS_) * g[co];
    float sh = bb[co] - m[co] * sc;
    float4 lv = lp[co * (NPIX / 4)];
    float4 av = ap[co * (NPIX / 4)];
    float4 r;
    float gx = 1.f / (1.f + __expf(-(acc.x * sc + sh)));
    float gy = 1.f / (1.f + __expf(-(acc.y * sc + sh)));
    float gz = 1.f / (1.f + __expf(-(acc.z * sc + sh)));
    float gw = 1.f / (1.f + __expf(-(acc.w * sc + sh)));
    r.x = gx * lv.x + (1.f - gx) * av.x;
    r.y = gy * lv.y + (1.f - gy) * av.y;
    r.z = gz * lv.z + (1.f - gz) * av.z;
    r.w = gw * lv.w + (1.f - gw) * av.w;
    *(float4*)(fused + ((size_t)b * CO_ + co) * NPIX + n4) = r;
}

// final: relu(bn4(Wf @ [fused;local;attn])) + rs*(Wr @ x), 4-wide
__global__ __launch_bounds__(256) void z_out4(
    const float* __restrict__ fused, const float* __restrict__ local, const float* __restrict__ attn,
    const float* __restrict__ x, const float* __restrict__ Wf, const float* __restrict__ bfb,
    const float* __restrict__ g, const float* __restrict__ bb,
    const float* __restrict__ m, const float* __restrict__ v,
    const float* __restrict__ Wr, const float* __restrict__ rsp, float* __restrict__ out)
{
    int i = blockIdx.x * 256 + threadIdx.x;
    int n4 = (i & 1023) * 4;
    int co = (i >> 10) & (CO_ - 1);
    int b = i >> 17;
    const float4* fp = (const float4*)(fused + (size_t)b * CO_ * NPIX + n4);
    const float4* lp = (const float4*)(local + (size_t)b * CO_ * NPIX + n4);
    const float4* ap = (const float4*)(attn + (size_t)b * CO_ * NPIX + n4);
    const float* wp = Wf + co * 3 * CO_;
    float4 acc;
    acc.x = acc.y = acc.z = acc.w = bfb[co];
#pragma unroll 8
    for (int cc = 0; cc < CO_; ++cc) {
        float4 fv = fp[cc * (NPIX / 4)];
        float w = wp[cc];
        acc.x += w * fv.x; acc.y += w * fv.y; acc.z += w * fv.z; acc.w += w * fv.w;
    }
#pragma unroll 8
    for (int cc = 0; cc < CO_; ++cc) {
        float4 lv = lp[cc * (NPIX / 4)];
        float w = wp[CO_ + cc];
        acc.x += w * lv.x; acc.y += w * lv.y; acc.z += w * lv.z; acc.w += w * lv.w;
    }
#pragma unroll 8
    for (int cc = 0; cc < CO_; ++cc) {
        float4 av = ap[cc * (NPIX / 4)];
        float w = wp[2 * CO_ + cc];
        acc.x += w * av.x; acc.y += w * av.y; acc.z += w * av.z; acc.w += w * av.w;
    }
    float sc = rsqrtf(v[co] + EPS_) * g[co];
    float sh = bb[co] - m[co] * sc;
    float4 r;
    r.x = fmaxf(acc.x * sc + sh, 0.f);
    r.y = fmaxf(acc.y * sc + sh, 0.f);
    r.z = fmaxf(acc.z * sc + sh, 0.f);
    r.w = fmaxf(acc.w * sc + sh, 0.f);
    const float4* xp = (const float4*)(x + (size_t)b * CI_ * NPIX + n4);
    const float* wr = Wr + co * CI_;
    float4 rr;
    rr.x = rr.y = rr.z = rr.w = 0.f;
#pragma unroll 8
    for (int ci = 0; ci < CI_; ++ci) {
        float4 xv = xp[ci * (NPIX / 4)];
        float w = wr[ci];
        rr.x += w * xv.x; rr.y += w * xv.y; rr.z += w * xv.z; rr.w += w * xv.w;
    }
    float rsv = rsp[0];
    r.x += rsv * rr.x; r.y += rsv * rr.y; r.z += rsv * rr.z; r.w += rsv * rr.w;
    *(float4*)(out + ((size_t)b * CO_ + co) * NPIX + n4) = r;
}

extern "C" void kernel_launch(void* const* d_in, const int* in_sizes, int n_in,
                              void* d_out, int out_size, void* d_ws, size_t ws_size,
                              hipStream_t stream) {
    const float* x   = (const float*)d_in[0];
    const float* W3  = (const float*)d_in[1];
    const float* b3  = (const float*)d_in[2];
    const float* g1  = (const float*)d_in[3];
    const float* b1  = (const float*)d_in[4];
    const float* m1  = (const float*)d_in[5];
    const float* v1  = (const float*)d_in[6];
    const float* Wa  = (const float*)d_in[7];
    const float* ba  = (const float*)d_in[8];
    const float* g2  = (const float*)d_in[9];
    const float* b2  = (const float*)d_in[10];
    const float* m2  = (const float*)d_in[11];
    const float* v2  = (const float*)d_in[12];
    const float* Wq  = (const float*)d_in[13];
    const float* bq  = (const float*)d_in[14];
    const float* Wk  = (const float*)d_in[15];
    const float* bk  = (const float*)d_in[16];
    const float* Wv  = (const float*)d_in[17];
    const float* bv  = (const float*)d_in[18];
    const float* gam = (const float*)d_in[19];
    const float* Wg  = (const float*)d_in[20];
    const float* bg  = (const float*)d_in[21];
    const float* g3  = (const float*)d_in[22];
    const float* b3n = (const float*)d_in[23];
    const float* m3  = (const float*)d_in[24];
    const float* v3  = (const float*)d_in[25];
    const float* Wf  = (const float*)d_in[26];
    const float* bfb = (const float*)d_in[27];
    const float* g4  = (const float*)d_in[28];
    const float* b4  = (const float*)d_in[29];
    const float* m4  = (const float*)d_in[30];
    const float* v4  = (const float*)d_in[31];
    const float* Wr  = (const float*)d_in[32];
    const float* rs  = (const float*)d_in[33];

    float* ws    = (float*)d_ws;
    float* a_    = ws;                  // [0, 2M) floats
    float* local = ws + 2097152;        // [2M, 4M)
    float* attn  = ws + 4194304;        // [4M, 6M)
    float* vT    = ws + 6291456;        // [6M, 8M); fused aliases (vT dead after z_attn2)
    float* q     = ws + 8388608;        // 262,144
    float* kk    = ws + 8650752;        // 262,144  -> total 34 MiB
    float* fused = vT;

    float* out = (float*)d_out;

    z_proj_a4<<<2048, 256, 0, stream>>>(x, Wa, ba, g2, b2, m2, v2, a_);
    z_projqk<<<1024, 256, 0, stream>>>(a_, Wq, bq, q);
    z_projqk<<<1024, 256, 0, stream>>>(a_, Wk, bk, kk);
    z_projv<<<8192, 256, 0, stream>>>(a_, Wv, bv, vT);
    z_attn2<<<1024, 256, 0, stream>>>(q, kk, vT, a_, gam, attn);
    z_conv3<<<8192, 256, 0, stream>>>(x, W3, b3, g1, b1, m1, v1, local);
    z_gate4<<<2048, 256, 0, stream>>>(local, attn, Wg, bg, g3, b3n, m3, v3, fused);
    z_out4<<<2048, 256, 0, stream>>>(fused, local, attn, x, Wf, bfb, g4, b4, m4, v4, Wr, rs, out);
}

// Round 8
// 1076.742 us; speedup vs baseline: 3.0860x; 1.7149x over previous
//
#include <hip/hip_runtime.h>
#include <hip/hip_bf16.h>

#define CI_ 64
#define CO_ 128
#define NPIX 4096
#define CQ_ 16
#define QT 16
#define MT 256
#define EPS_ 1e-5f

// a = relu(bn2(Wa @ x + ba)), 4 outputs per thread along n
__global__ __launch_bounds__(256) void z_proj_a4(
    const float* __restrict__ x, const float* __restrict__ Wa, const float* __restrict__ ba,
    const float* __restrict__ g, const float* __restrict__ bb,
    const float* __restrict__ m, const float* __restrict__ v, float* __restrict__ a)
{
    int i = blockIdx.x * 256 + threadIdx.x;   // B*CO*1024
    int n4 = (i & 1023) * 4;
    int co = (i >> 10) & (CO_ - 1);
    int b = i >> 17;
    const float4* xp = (const float4*)(x + (size_t)b * CI_ * NPIX + n4);
    const float* wp = Wa + co * CI_;
    float4 acc;
    acc.x = acc.y = acc.z = acc.w = ba[co];
#pragma unroll 8
    for (int ci = 0; ci < CI_; ++ci) {
        float4 xv = xp[ci * (NPIX / 4)];
        float w = wp[ci];
        acc.x += w * xv.x; acc.y += w * xv.y; acc.z += w * xv.z; acc.w += w * xv.w;
    }
    float sc = rsqrtf(v[co] + EPS_) * g[co];
    float sh = bb[co] - m[co] * sc;
    float4 r;
    r.x = fmaxf(acc.x * sc + sh, 0.f);
    r.y = fmaxf(acc.y * sc + sh, 0.f);
    r.z = fmaxf(acc.z * sc + sh, 0.f);
    r.w = fmaxf(acc.w * sc + sh, 0.f);
    *(float4*)(a + ((size_t)b * CO_ + co) * NPIX + n4) = r;
}

// LDS-tiled conv3x3 + BN + ReLU.
// grid: b(4) x co-group(16 of 8) x h-strip(8 of 8) = 512 blocks, 256 thr.
__global__ __launch_bounds__(256) void z_conv3t(
    const float* __restrict__ x, const float* __restrict__ W3, const float* __restrict__ b3,
    const float* __restrict__ g, const float* __restrict__ bb,
    const float* __restrict__ m, const float* __restrict__ v, float* __restrict__ local)
{
    __shared__ float xs[8][10][66];   // ci-chunk 8, rows h0-1..h0+8, cols -1..64 (21120B)
    __shared__ float wsm[8][8][9];    // [co_local][ci_local][tap] (2304B)

    int blk = blockIdx.x;
    int b  = blk >> 7;
    int cg = (blk >> 3) & 15;
    int hs = blk & 7;
    int co0 = cg * 8, h0 = hs * 8;

    int tid = threadIdx.x;
    int w = tid & 63;
    int cl = tid >> 6;                 // 0..3, handles co pair (2cl, 2cl+1)
    int coA = co0 + 2 * cl, coB = coA + 1;

    float acc[2][8];
#pragma unroll
    for (int hh = 0; hh < 8; ++hh) { acc[0][hh] = b3[coA]; acc[1][hh] = b3[coB]; }

    for (int ci0 = 0; ci0 < CI_; ci0 += 8) {
        // stage x tile (zero-padded halo)
        for (int l = tid; l < 8 * 10 * 66; l += 256) {
            int ci = l / 660;
            int rem = l - ci * 660;
            int r = rem / 66;
            int col = rem - r * 66;
            int hh = h0 + r - 1;
            int wg = col - 1;
            float val = 0.f;
            if ((unsigned)hh < 64u && (unsigned)wg < 64u)
                val = x[((size_t)b * CI_ + ci0 + ci) * NPIX + hh * 64 + wg];
            xs[ci][r][col] = val;
        }
        // stage weights
        for (int l = tid; l < 8 * 8 * 9; l += 256) {
            int co = l / 72;
            int rem = l - co * 72;
            int ci = rem / 9;
            int tap = rem - ci * 9;
            wsm[co][ci][tap] = W3[((size_t)(co0 + co) * CI_ + ci0 + ci) * 9 + tap];
        }
        __syncthreads();

#pragma unroll
        for (int ci = 0; ci < 8; ++ci) {
            float x0[10], x1[10], x2[10];
#pragma unroll
            for (int r = 0; r < 10; ++r) {
                x0[r] = xs[ci][r][w];
                x1[r] = xs[ci][r][w + 1];
                x2[r] = xs[ci][r][w + 2];
            }
#pragma unroll
            for (int cc = 0; cc < 2; ++cc) {
                const float* wt = &wsm[2 * cl + cc][ci][0];
                float w00 = wt[0], w01 = wt[1], w02 = wt[2];
                float w10 = wt[3], w11 = wt[4], w12 = wt[5];
                float w20 = wt[6], w21 = wt[7], w22 = wt[8];
#pragma unroll
                for (int hh = 0; hh < 8; ++hh) {
                    float s = acc[cc][hh];
                    s += w00 * x0[hh]     + w01 * x1[hh]     + w02 * x2[hh];
                    s += w10 * x0[hh + 1] + w11 * x1[hh + 1] + w12 * x2[hh + 1];
                    s += w20 * x0[hh + 2] + w21 * x1[hh + 2] + w22 * x2[hh + 2];
                    acc[cc][hh] = s;
                }
            }
        }
        __syncthreads();
    }

#pragma unroll
    for (int cc = 0; cc < 2; ++cc) {
        int co = coA + cc;
        float sc = rsqrtf(v[co] + EPS_) * g[co];
        float sh = bb[co] - m[co] * sc;
#pragma unroll
        for (int hh = 0; hh < 8; ++hh) {
            float y = fmaxf(acc[cc][hh] * sc + sh, 0.f);
            local[((size_t)b * CO_ + co) * NPIX + (h0 + hh) * 64 + w] = y;
        }
    }
}

// q/k projection (Cout=16)
__global__ __launch_bounds__(256) void z_projqk(
    const float* __restrict__ a, const float* __restrict__ W, const float* __restrict__ bias,
    float* __restrict__ out)
{
    int i = blockIdx.x * 256 + threadIdx.x;
    int n = i & (NPIX - 1);
    int c = (i >> 12) & (CQ_ - 1);
    int b = i >> 16;
    const float* ap = a + (size_t)b * CO_ * NPIX + n;
    const float* wp = W + c * CO_;
    float acc = bias[c];
#pragma unroll 8
    for (int t = 0; t < CO_; ++t) acc += wp[t] * ap[t * NPIX];
    out[i] = acc;
}

// vT[b][n][c] = Wv[c,:] . a[b,:,n] + bv[c]
__global__ __launch_bounds__(256) void z_projv(
    const float* __restrict__ a, const float* __restrict__ Wv, const float* __restrict__ bv,
    float* __restrict__ vT)
{
    int i = blockIdx.x * 256 + threadIdx.x;
    int c = i & (CO_ - 1);
    int n = (i >> 7) & (NPIX - 1);
    int b = i >> 19;
    const float* ap = a + (size_t)b * CO_ * NPIX + n;
    const float* wp = Wv + c * CO_;
    float acc = bv[c];
#pragma unroll 8
    for (int t = 0; t < CO_; ++t) acc += wp[t] * ap[t * NPIX];
    vT[i] = acc;
}

// flash attention: QT=16 queries per block, KV tiled by MT=256.
// attn[idx] = gam * o + a[idx]
__global__ __launch_bounds__(256) void z_attn2(
    const float* __restrict__ q, const float* __restrict__ k, const float* __restrict__ vT,
    const float* __restrict__ a, const float* __restrict__ gamp, float* __restrict__ attn)
{
    __shared__ float qs[QT][CQ_];
    __shared__ float p[QT][260];
    __shared__ float rmax[QT], rsum[QT], rf[QT], rnm[QT];
    int tid = threadIdx.x;
    int b = blockIdx.x >> 8;
    int q0 = (blockIdx.x & 255) * QT;

    if (tid < QT * CQ_) {
        int qi = tid >> 4, c = tid & 15;
        qs[qi][c] = q[((size_t)b * CQ_ + c) * NPIX + q0 + qi];
    }
    if (tid < QT) { rmax[tid] = -1e30f; rsum[tid] = 0.f; }

    int c = tid & 127;
    int half = tid >> 7;
    float o[QT];
#pragma unroll
    for (int i = 0; i < QT; ++i) o[i] = 0.f;

    __syncthreads();

    for (int t = 0; t < NPIX / MT; ++t) {
        int m0 = t * MT;
        float kv[CQ_];
#pragma unroll
        for (int cc = 0; cc < CQ_; ++cc) kv[cc] = k[((size_t)b * CQ_ + cc) * NPIX + m0 + tid];
        float s[QT];
#pragma unroll
        for (int qi = 0; qi < QT; ++qi) {
            float acc = 0.f;
#pragma unroll
            for (int cc = 0; cc < CQ_; ++cc) acc += qs[qi][cc] * kv[cc];
            s[qi] = acc;
            p[qi][tid] = acc;
        }
        __syncthreads();
        {
            int gq = tid >> 4, j = tid & 15;
            float mx = -1e30f;
#pragma unroll
            for (int i2 = 0; i2 < 16; ++i2) mx = fmaxf(mx, p[gq][j + 16 * i2]);
#pragma unroll
            for (int off = 8; off; off >>= 1) mx = fmaxf(mx, __shfl_xor(mx, off, 16));
            if (j == 0) {
                float om = rmax[gq];
                float nm = fmaxf(om, mx);
                rf[gq] = __expf(om - nm);
                rnm[gq] = nm;
                rmax[gq] = nm;
            }
        }
        __syncthreads();
#pragma unroll
        for (int qi = 0; qi < QT; ++qi) p[qi][tid] = __expf(s[qi] - rnm[qi]);
        __syncthreads();
        {
            int gq = tid >> 4, j = tid & 15;
            float sm = 0.f;
#pragma unroll
            for (int i2 = 0; i2 < 16; ++i2) sm += p[gq][j + 16 * i2];
#pragma unroll
            for (int off = 8; off; off >>= 1) sm += __shfl_xor(sm, off, 16);
            if (j == 0) rsum[gq] = rsum[gq] * rf[gq] + sm;
        }
#pragma unroll
        for (int qi = 0; qi < QT; ++qi) o[qi] *= rf[qi];
        const float* vp = vT + (size_t)b * NPIX * CO_ + (size_t)(m0 + half * 128) * CO_ + c;
#pragma unroll 2
        for (int mm = 0; mm < 128; mm += 4) {
            float v0 = vp[(mm + 0) * CO_];
            float v1 = vp[(mm + 1) * CO_];
            float v2 = vp[(mm + 2) * CO_];
            float v3 = vp[(mm + 3) * CO_];
            int mb = half * 128 + mm;
#pragma unroll
            for (int qi = 0; qi < QT; ++qi) {
                float4 pv = *(const float4*)(&p[qi][mb]);
                o[qi] += pv.x * v0 + pv.y * v1 + pv.z * v2 + pv.w * v3;
            }
        }
        __syncthreads();
    }

    float* otile = &p[0][0];
    if (half == 0) {
#pragma unroll
        for (int qi = 0; qi < QT; ++qi) otile[qi * 132 + c] = o[qi];
    }
    __syncthreads();
    if (half == 1) {
#pragma unroll
        for (int qi = 0; qi < QT; ++qi) otile[qi * 132 + c] += o[qi];
    }
    __syncthreads();
    float gam = gamp[0];
    int qi = tid & 15;
    float inv = 1.f / rsum[qi];
#pragma unroll
    for (int j = 0; j < 8; ++j) {
        int cc = (tid >> 4) + 16 * j;
        size_t idx = ((size_t)b * CO_ + cc) * NPIX + q0 + qi;
        attn[idx] = gam * (otile[qi * 132 + cc] * inv) + a[idx];
    }
}

// gate + fuse, 4-wide along n
__global__ __launch_bounds__(256) void z_gate4(
    const float* __restrict__ local, const float* __restrict__ attn,
    const float* __restrict__ Wg, const float* __restrict__ bg,
    const float* __restrict__ g, const float* __restrict__ bb,
    const float* __restrict__ m, const float* __restrict__ v, float* __restrict__ fused)
{
    int i = blockIdx.x * 256 + threadIdx.x;
    int n4 = (i & 1023) * 4;
    int co = (i >> 10) & (CO_ - 1);
    int b = i >> 17;
    const float4* lp = (const float4*)(local + (size_t)b * CO_ * NPIX + n4);
    const float4* ap = (const float4*)(attn + (size_t)b * CO_ * NPIX + n4);
    const float* wp = Wg + co * 2 * CO_;
    float4 acc;
    acc.x = acc.y = acc.z = acc.w = bg[co];
#pragma unroll 8
    for (int cc = 0; cc < CO_; ++cc) {
        float4 lv = lp[cc * (NPIX / 4)];
        float w = wp[cc];
        acc.x += w * lv.x; acc.y += w * lv.y; acc.z += w * lv.z; acc.w += w * lv.w;
    }
#pragma unroll 8
    for (int cc = 0; cc < CO_; ++cc) {
        float4 av = ap[cc * (NPIX / 4)];
        float w = wp[CO_ + cc];
        acc.x += w * av.x; acc.y += w * av.y; acc.z += w * av.z; acc.w += w * av.w;
    }
    float sc = rsqrtf(v[co] + EPS_) * g[co];
    float sh = bb[co] - m[co] * sc;
    float4 lv = lp[co * (NPIX / 4)];
    float4 av = ap[co * (NPIX / 4)];
    float4 r;
    float gx = 1.f / (1.f + __expf(-(acc.x * sc + sh)));
    float gy = 1.f / (1.f + __expf(-(acc.y * sc + sh)));
    float gz = 1.f / (1.f + __expf(-(acc.z * sc + sh)));
    float gw = 1.f / (1.f + __expf(-(acc.w * sc + sh)));
    r.x = gx * lv.x + (1.f - gx) * av.x;
    r.y = gy * lv.y + (1.f - gy) * av.y;
    r.z = gz * lv.z + (1.f - gz) * av.z;
    r.w = gw * lv.w + (1.f - gw) * av.w;
    *(float4*)(fused + ((size_t)b * CO_ + co) * NPIX + n4) = r;
}

// final: relu(bn4(Wf @ [fused;local;attn])) + rs*(Wr @ x), 4-wide
__global__ __launch_bounds__(256) void z_out4(
    const float* __restrict__ fused, const float* __restrict__ local, const float* __restrict__ attn,
    const float* __restrict__ x, const float* __restrict__ Wf, const float* __restrict__ bfb,
    const float* __restrict__ g, const float* __restrict__ bb,
    const float* __restrict__ m, const float* __restrict__ v,
    const float* __restrict__ Wr, const float* __restrict__ rsp, float* __restrict__ out)
{
    int i = blockIdx.x * 256 + threadIdx.x;
    int n4 = (i & 1023) * 4;
    int co = (i >> 10) & (CO_ - 1);
    int b = i >> 17;
    const float4* fp = (const float4*)(fused + (size_t)b * CO_ * NPIX + n4);
    const float4* lp = (const float4*)(local + (size_t)b * CO_ * NPIX + n4);
    const float4* ap = (const float4*)(attn + (size_t)b * CO_ * NPIX + n4);
    const float* wp = Wf + co * 3 * CO_;
    float4 acc;
    acc.x = acc.y = acc.z = acc.w = bfb[co];
#pragma unroll 8
    for (int cc = 0; cc < CO_; ++cc) {
        float4 fv = fp[cc * (NPIX / 4)];
        float w = wp[cc];
        acc.x += w * fv.x; acc.y += w * fv.y; acc.z += w * fv.z; acc.w += w * fv.w;
    }
#pragma unroll 8
    for (int cc = 0; cc < CO_; ++cc) {
        float4 lv = lp[cc * (NPIX / 4)];
        float w = wp[CO_ + cc];
        acc.x += w * lv.x; acc.y += w * lv.y; acc.z += w * lv.z; acc.w += w * lv.w;
    }
#pragma unroll 8
    for (int cc = 0; cc < CO_; ++cc) {
        float4 av = ap[cc * (NPIX / 4)];
        float w = wp[2 * CO_ + cc];
        acc.x += w * av.x; acc.y += w * av.y; acc.z += w * av.z; acc.w += w * av.w;
    }
    float sc = rsqrtf(v[co] + EPS_) * g[co];
    float sh = bb[co] - m[co] * sc;
    float4 r;
    r.x = fmaxf(acc.x * sc + sh, 0.f);
    r.y = fmaxf(acc.y * sc + sh, 0.f);
    r.z = fmaxf(acc.z * sc + sh, 0.f);
    r.w = fmaxf(acc.w * sc + sh, 0.f);
    const float4* xp = (const float4*)(x + (size_t)b * CI_ * NPIX + n4);
    const float* wr = Wr + co * CI_;
    float4 rr;
    rr.x = rr.y = rr.z = rr.w = 0.f;
#pragma unroll 8
    for (int ci = 0; ci < CI_; ++ci) {
        float4 xv = xp[ci * (NPIX / 4)];
        float w = wr[ci];
        rr.x += w * xv.x; rr.y += w * xv.y; rr.z += w * xv.z; rr.w += w * xv.w;
    }
    float rsv = rsp[0];
    r.x += rsv * rr.x; r.y += rsv * rr.y; r.z += rsv * rr.z; r.w += rsv * rr.w;
    *(float4*)(out + ((size_t)b * CO_ + co) * NPIX + n4) = r;
}

extern "C" void kernel_launch(void* const* d_in, const int* in_sizes, int n_in,
                              void* d_out, int out_size, void* d_ws, size_t ws_size,
                              hipStream_t stream) {
    const float* x   = (const float*)d_in[0];
    const float* W3  = (const float*)d_in[1];
    const float* b3  = (const float*)d_in[2];
    const float* g1  = (const float*)d_in[3];
    const float* b1  = (const float*)d_in[4];
    const float* m1  = (const float*)d_in[5];
    const float* v1  = (const float*)d_in[6];
    const float* Wa  = (const float*)d_in[7];
    const float* ba  = (const float*)d_in[8];
    const float* g2  = (const float*)d_in[9];
    const float* b2  = (const float*)d_in[10];
    const float* m2  = (const float*)d_in[11];
    const float* v2  = (const float*)d_in[12];
    const float* Wq  = (const float*)d_in[13];
    const float* bq  = (const float*)d_in[14];
    const float* Wk  = (const float*)d_in[15];
    const float* bk  = (const float*)d_in[16];
    const float* Wv  = (const float*)d_in[17];
    const float* bv  = (const float*)d_in[18];
    const float* gam = (const float*)d_in[19];
    const float* Wg  = (const float*)d_in[20];
    const float* bg  = (const float*)d_in[21];
    const float* g3  = (const float*)d_in[22];
    const float* b3n = (const float*)d_in[23];
    const float* m3  = (const float*)d_in[24];
    const float* v3  = (const float*)d_in[25];
    const float* Wf  = (const float*)d_in[26];
    const float* bfb = (const float*)d_in[27];
    const float* g4  = (const float*)d_in[28];
    const float* b4  = (const float*)d_in[29];
    const float* m4  = (const float*)d_in[30];
    const float* v4  = (const float*)d_in[31];
    const float* Wr  = (const float*)d_in[32];
    const float* rs  = (const float*)d_in[33];

    float* ws    = (float*)d_ws;
    float* a_    = ws;                  // [0, 2M) floats
    float* local = ws + 2097152;        // [2M, 4M)
    float* attn  = ws + 4194304;        // [4M, 6M)
    float* vT    = ws + 6291456;        // [6M, 8M); fused aliases (vT dead after z_attn2)
    float* q     = ws + 8388608;        // 262,144
    float* kk    = ws + 8650752;        // 262,144  -> total 34 MiB
    float* fused = vT;

    float* out = (float*)d_out;

    z_proj_a4<<<2048, 256, 0, stream>>>(x, Wa, ba, g2, b2, m2, v2, a_);
    z_projqk<<<1024, 256, 0, stream>>>(a_, Wq, bq, q);
    z_projqk<<<1024, 256, 0, stream>>>(a_, Wk, bk, kk);
    z_projv<<<8192, 256, 0, stream>>>(a_, Wv, bv, vT);
    z_attn2<<<1024, 256, 0, stream>>>(q, kk, vT, a_, gam, attn);
    z_conv3t<<<512, 256, 0, stream>>>(x, W3, b3, g1, b1, m1, v1, local);
    z_gate4<<<2048, 256, 0, stream>>>(local, attn, Wg, bg, g3, b3n, m3, v3, fused);
    z_out4<<<2048, 256, 0, stream>>>(fused, local, attn, x, Wf, bfb, g4, b4, m4, v4, Wr, rs, out);
}

// Round 9
// 571.921 us; speedup vs baseline: 5.8100x; 1.8827x over previous
//
#include <hip/hip_runtime.h>
#include <hip/hip_bf16.h>

#define CI_ 64
#define CO_ 128
#define NPIX 4096
#define CQ_ 16
#define QT 16
#define MT 256
#define EPS_ 1e-5f

typedef __attribute__((ext_vector_type(8))) __bf16 bf16x8;
typedef __attribute__((ext_vector_type(4))) float f32x4;

// a = relu(bn2(Wa @ x + ba)), 4 outputs per thread along n
__global__ __launch_bounds__(256) void z_proj_a4(
    const float* __restrict__ x, const float* __restrict__ Wa, const float* __restrict__ ba,
    const float* __restrict__ g, const float* __restrict__ bb,
    const float* __restrict__ m, const float* __restrict__ v, float* __restrict__ a)
{
    int i = blockIdx.x * 256 + threadIdx.x;   // B*CO*1024
    int n4 = (i & 1023) * 4;
    int co = (i >> 10) & (CO_ - 1);
    int b = i >> 17;
    const float4* xp = (const float4*)(x + (size_t)b * CI_ * NPIX + n4);
    const float* wp = Wa + co * CI_;
    float4 acc;
    acc.x = acc.y = acc.z = acc.w = ba[co];
#pragma unroll 8
    for (int ci = 0; ci < CI_; ++ci) {
        float4 xv = xp[ci * (NPIX / 4)];
        float w = wp[ci];
        acc.x += w * xv.x; acc.y += w * xv.y; acc.z += w * xv.z; acc.w += w * xv.w;
    }
    float sc = rsqrtf(v[co] + EPS_) * g[co];
    float sh = bb[co] - m[co] * sc;
    float4 r;
    r.x = fmaxf(acc.x * sc + sh, 0.f);
    r.y = fmaxf(acc.y * sc + sh, 0.f);
    r.z = fmaxf(acc.z * sc + sh, 0.f);
    r.w = fmaxf(acc.w * sc + sh, 0.f);
    *(float4*)(a + ((size_t)b * CO_ + co) * NPIX + n4) = r;
}

// LDS-tiled conv3x3 + BN + ReLU (unchanged from round 8)
__global__ __launch_bounds__(256) void z_conv3t(
    const float* __restrict__ x, const float* __restrict__ W3, const float* __restrict__ b3,
    const float* __restrict__ g, const float* __restrict__ bb,
    const float* __restrict__ m, const float* __restrict__ v, float* __restrict__ local)
{
    __shared__ float xs[8][10][66];
    __shared__ float wsm[8][8][9];

    int blk = blockIdx.x;
    int b  = blk >> 7;
    int cg = (blk >> 3) & 15;
    int hs = blk & 7;
    int co0 = cg * 8, h0 = hs * 8;

    int tid = threadIdx.x;
    int w = tid & 63;
    int cl = tid >> 6;
    int coA = co0 + 2 * cl, coB = coA + 1;

    float acc[2][8];
#pragma unroll
    for (int hh = 0; hh < 8; ++hh) { acc[0][hh] = b3[coA]; acc[1][hh] = b3[coB]; }

    for (int ci0 = 0; ci0 < CI_; ci0 += 8) {
        for (int l = tid; l < 8 * 10 * 66; l += 256) {
            int ci = l / 660;
            int rem = l - ci * 660;
            int r = rem / 66;
            int col = rem - r * 66;
            int hh = h0 + r - 1;
            int wg = col - 1;
            float val = 0.f;
            if ((unsigned)hh < 64u && (unsigned)wg < 64u)
                val = x[((size_t)b * CI_ + ci0 + ci) * NPIX + hh * 64 + wg];
            xs[ci][r][col] = val;
        }
        for (int l = tid; l < 8 * 8 * 9; l += 256) {
            int co = l / 72;
            int rem = l - co * 72;
            int ci = rem / 9;
            int tap = rem - ci * 9;
            wsm[co][ci][tap] = W3[((size_t)(co0 + co) * CI_ + ci0 + ci) * 9 + tap];
        }
        __syncthreads();

#pragma unroll
        for (int ci = 0; ci < 8; ++ci) {
            float x0[10], x1[10], x2[10];
#pragma unroll
            for (int r = 0; r < 10; ++r) {
                x0[r] = xs[ci][r][w];
                x1[r] = xs[ci][r][w + 1];
                x2[r] = xs[ci][r][w + 2];
            }
#pragma unroll
            for (int cc = 0; cc < 2; ++cc) {
                const float* wt = &wsm[2 * cl + cc][ci][0];
                float w00 = wt[0], w01 = wt[1], w02 = wt[2];
                float w10 = wt[3], w11 = wt[4], w12 = wt[5];
                float w20 = wt[6], w21 = wt[7], w22 = wt[8];
#pragma unroll
                for (int hh = 0; hh < 8; ++hh) {
                    float s = acc[cc][hh];
                    s += w00 * x0[hh]     + w01 * x1[hh]     + w02 * x2[hh];
                    s += w10 * x0[hh + 1] + w11 * x1[hh + 1] + w12 * x2[hh + 1];
                    s += w20 * x0[hh + 2] + w21 * x1[hh + 2] + w22 * x2[hh + 2];
                    acc[cc][hh] = s;
                }
            }
        }
        __syncthreads();
    }

#pragma unroll
    for (int cc = 0; cc < 2; ++cc) {
        int co = coA + cc;
        float sc = rsqrtf(v[co] + EPS_) * g[co];
        float sh = bb[co] - m[co] * sc;
#pragma unroll
        for (int hh = 0; hh < 8; ++hh) {
            float y = fmaxf(acc[cc][hh] * sc + sh, 0.f);
            local[((size_t)b * CO_ + co) * NPIX + (h0 + hh) * 64 + w] = y;
        }
    }
}

// q/k projection (Cout=16)
__global__ __launch_bounds__(256) void z_projqk(
    const float* __restrict__ a, const float* __restrict__ W, const float* __restrict__ bias,
    float* __restrict__ out)
{
    int i = blockIdx.x * 256 + threadIdx.x;
    int n = i & (NPIX - 1);
    int c = (i >> 12) & (CQ_ - 1);
    int b = i >> 16;
    const float* ap = a + (size_t)b * CO_ * NPIX + n;
    const float* wp = W + c * CO_;
    float acc = bias[c];
#pragma unroll 8
    for (int t = 0; t < CO_; ++t) acc += wp[t] * ap[t * NPIX];
    out[i] = acc;
}

// V2[b][n/8][c][8] bf16 = Wv @ a + bv  (pre-swizzled for MFMA B-fragments)
__global__ __launch_bounds__(256) void z_projv2(
    const float* __restrict__ a, const float* __restrict__ Wv, const float* __restrict__ bv,
    __bf16* __restrict__ V2)
{
    __shared__ __bf16 wsm[128 * 130];       // bf16 weights, padded stride
    int tid = threadIdx.x;
    int blk = blockIdx.x;
    int b = blk >> 8;
    int ng = blk & 255;

    for (int i = tid; i < 128 * 128; i += 256) {
        int c = i >> 7, t = i & 127;
        wsm[c * 130 + t] = (__bf16)Wv[i];
    }
    __syncthreads();

    int c = tid & 127;
    int n8 = ng * 2 + (tid >> 7);            // 0..511
    float acc[8];
    float bvc = bv[c];
#pragma unroll
    for (int j = 0; j < 8; ++j) acc[j] = bvc;

    const float4* a4 = (const float4*)(a + (size_t)b * CO_ * NPIX);
#pragma unroll 4
    for (int t = 0; t < 128; ++t) {
        float w = (float)wsm[c * 130 + t];
        float4 a0 = a4[t * 1024 + n8 * 2];
        float4 a1 = a4[t * 1024 + n8 * 2 + 1];
        acc[0] += w * a0.x; acc[1] += w * a0.y; acc[2] += w * a0.z; acc[3] += w * a0.w;
        acc[4] += w * a1.x; acc[5] += w * a1.y; acc[6] += w * a1.z; acc[7] += w * a1.w;
    }
    bf16x8 r;
#pragma unroll
    for (int j = 0; j < 8; ++j) r[j] = (__bf16)acc[j];
    ((bf16x8*)V2)[(size_t)b * 65536 + n8 * 128 + c] = r;
}

// flash attention with MFMA PV. QT=16 queries/block, MT=256 m-tile.
// attn[idx] = gam * o + a[idx]
__global__ __launch_bounds__(256) void z_attn3(
    const float* __restrict__ q, const float* __restrict__ k, const __bf16* __restrict__ V2,
    const float* __restrict__ a, const float* __restrict__ gamp, float* __restrict__ attn)
{
    __shared__ float qs[QT][CQ_];
    __shared__ __align__(16) float s_lds[16 * 260];    // raw scores; aliased as o_lds at end
    __shared__ __align__(16) __bf16 p_lds[16 * 264];   // exp'd P in bf16
    __shared__ float rmax[16], rsum[16], rff[16], rnm[16];

    int tid = threadIdx.x;
    int b = blockIdx.x >> 8;
    int q0 = (blockIdx.x & 255) * QT;
    int l = tid & 63;
    int w = tid >> 6;                 // wave id: c-slice [w*32, w*32+32)
    int arow = l & 15;
    int agrp = l >> 4;                // 0..3

    if (tid < QT * CQ_) {
        int qi = tid >> 4, c = tid & 15;
        qs[qi][c] = q[((size_t)b * CQ_ + c) * NPIX + q0 + qi];
    }
    if (tid < 16) { rmax[tid] = -1e30f; rsum[tid] = 0.f; }

    f32x4 acc0 = {0.f, 0.f, 0.f, 0.f};
    f32x4 acc1 = {0.f, 0.f, 0.f, 0.f};
    int c0 = w * 32 + (l & 15);
    int c1 = c0 + 16;
    const bf16x8* vbase = (const bf16x8*)V2 + (size_t)b * 65536;

    __syncthreads();

    for (int t = 0; t < NPIX / MT; ++t) {
        int m0 = t * MT;
        // scores for column m0+tid (fp32)
        float kv[CQ_];
#pragma unroll
        for (int cc = 0; cc < CQ_; ++cc) kv[cc] = k[((size_t)b * CQ_ + cc) * NPIX + m0 + tid];
        float s[QT];
#pragma unroll
        for (int qi = 0; qi < QT; ++qi) {
            float acc = 0.f;
#pragma unroll
            for (int cc = 0; cc < CQ_; ++cc) acc += qs[qi][cc] * kv[cc];
            s[qi] = acc;
            s_lds[qi * 260 + tid] = acc;
        }
        __syncthreads();
        // row max (group g handles query g)
        {
            int g = tid >> 4, j = tid & 15;
            float mx = -1e30f;
#pragma unroll
            for (int i2 = 0; i2 < 16; ++i2) mx = fmaxf(mx, s_lds[g * 260 + j + 16 * i2]);
#pragma unroll
            for (int off = 8; off; off >>= 1) mx = fmaxf(mx, __shfl_xor(mx, off, 16));
            if (j == 0) {
                float om = rmax[g];
                float nm = fmaxf(om, mx);
                rff[g] = __expf(om - nm);
                rnm[g] = nm;
                rmax[g] = nm;
            }
        }
        __syncthreads();
        // exp -> bf16 P
#pragma unroll
        for (int qi = 0; qi < QT; ++qi)
            p_lds[qi * 264 + tid] = (__bf16)__expf(s[qi] - rnm[qi]);
        __syncthreads();
        // row sum of bf16-rounded P (consistent with MFMA numerator)
        {
            int g = tid >> 4, j = tid & 15;
            float sm = 0.f;
#pragma unroll
            for (int i2 = 0; i2 < 16; ++i2) sm += (float)p_lds[g * 264 + j + 16 * i2];
#pragma unroll
            for (int off = 8; off; off >>= 1) sm += __shfl_xor(sm, off, 16);
            if (j == 0) rsum[g] = rsum[g] * rff[g] + sm;
        }
        // PV via MFMA: rescale acc, then accumulate this tile
        {
            float rf0 = rff[agrp * 4 + 0];
            float rf1 = rff[agrp * 4 + 1];
            float rf2 = rff[agrp * 4 + 2];
            float rf3 = rff[agrp * 4 + 3];
            acc0[0] *= rf0; acc0[1] *= rf1; acc0[2] *= rf2; acc0[3] *= rf3;
            acc1[0] *= rf0; acc1[1] *= rf1; acc1[2] *= rf2; acc1[3] *= rf3;
#pragma unroll
            for (int ks = 0; ks < 8; ++ks) {
                bf16x8 afrag = *(const bf16x8*)&p_lds[arow * 264 + ks * 32 + agrp * 8];
                int ms = (m0 >> 3) + ks * 4 + agrp;
                bf16x8 bf0 = vbase[ms * 128 + c0];
                bf16x8 bf1 = vbase[ms * 128 + c1];
                acc0 = __builtin_amdgcn_mfma_f32_16x16x32_bf16(afrag, bf0, acc0, 0, 0, 0);
                acc1 = __builtin_amdgcn_mfma_f32_16x16x32_bf16(afrag, bf1, acc1, 0, 0, 0);
            }
        }
        __syncthreads();   // protect s_lds/p_lds for next tile
    }

    // epilogue: stage o via LDS (alias s_lds), normalize, add gam*o + a
    float* o_lds = s_lds;              // [128][17]
#pragma unroll
    for (int r = 0; r < 4; ++r) {
        int qrow = agrp * 4 + r;
        o_lds[c0 * 17 + qrow] = acc0[r];
        o_lds[c1 * 17 + qrow] = acc1[r];
    }
    __syncthreads();
    float gam = gamp[0];
    int qi = tid & 15;
    float inv = 1.f / rsum[qi];
#pragma unroll
    for (int j = 0; j < 8; ++j) {
        int cc = (tid >> 4) + 16 * j;
        size_t idx = ((size_t)b * CO_ + cc) * NPIX + q0 + qi;
        attn[idx] = gam * (o_lds[cc * 17 + qi] * inv) + a[idx];
    }
}

// gate + fuse, 4-wide along n
__global__ __launch_bounds__(256) void z_gate4(
    const float* __restrict__ local, const float* __restrict__ attn,
    const float* __restrict__ Wg, const float* __restrict__ bg,
    const float* __restrict__ g, const float* __restrict__ bb,
    const float* __restrict__ m, const float* __restrict__ v, float* __restrict__ fused)
{
    int i = blockIdx.x * 256 + threadIdx.x;
    int n4 = (i & 1023) * 4;
    int co = (i >> 10) & (CO_ - 1);
    int b = i >> 17;
    const float4* lp = (const float4*)(local + (size_t)b * CO_ * NPIX + n4);
    const float4* ap = (const float4*)(attn + (size_t)b * CO_ * NPIX + n4);
    const float* wp = Wg + co * 2 * CO_;
    float4 acc;
    acc.x = acc.y = acc.z = acc.w = bg[co];
#pragma unroll 8
    for (int cc = 0; cc < CO_; ++cc) {
        float4 lv = lp[cc * (NPIX / 4)];
        float w = wp[cc];
        acc.x += w * lv.x; acc.y += w * lv.y; acc.z += w * lv.z; acc.w += w * lv.w;
    }
#pragma unroll 8
    for (int cc = 0; cc < CO_; ++cc) {
        float4 av = ap[cc * (NPIX / 4)];
        float w = wp[CO_ + cc];
        acc.x += w * av.x; acc.y += w * av.y; acc.z += w * av.z; acc.w += w * av.w;
    }
    float sc = rsqrtf(v[co] + EPS_) * g[co];
    float sh = bb[co] - m[co] * sc;
    float4 lv = lp[co * (NPIX / 4)];
    float4 av = ap[co * (NPIX / 4)];
    float4 r;
    float gx = 1.f / (1.f + __expf(-(acc.x * sc + sh)));
    float gy = 1.f / (1.f + __expf(-(acc.y * sc + sh)));
    float gz = 1.f / (1.f + __expf(-(acc.z * sc + sh)));
    float gw = 1.f / (1.f + __expf(-(acc.w * sc + sh)));
    r.x = gx * lv.x + (1.f - gx) * av.x;
    r.y = gy * lv.y + (1.f - gy) * av.y;
    r.z = gz * lv.z + (1.f - gz) * av.z;
    r.w = gw * lv.w + (1.f - gw) * av.w;
    *(float4*)(fused + ((size_t)b * CO_ + co) * NPIX + n4) = r;
}

// final: relu(bn4(Wf @ [fused;local;attn])) + rs*(Wr @ x), 4-wide
__global__ __launch_bounds__(256) void z_out4(
    const float* __restrict__ fused, const float* __restrict__ local, const float* __restrict__ attn,
    const float* __restrict__ x, const float* __restrict__ Wf, const float* __restrict__ bfb,
    const float* __restrict__ g, const float* __restrict__ bb,
    const float* __restrict__ m, const float* __restrict__ v,
    const float* __restrict__ Wr, const float* __restrict__ rsp, float* __restrict__ out)
{
    int i = blockIdx.x * 256 + threadIdx.x;
    int n4 = (i & 1023) * 4;
    int co = (i >> 10) & (CO_ - 1);
    int b = i >> 17;
    const float4* fp = (const float4*)(fused + (size_t)b * CO_ * NPIX + n4);
    const float4* lp = (const float4*)(local + (size_t)b * CO_ * NPIX + n4);
    const float4* ap = (const float4*)(attn + (size_t)b * CO_ * NPIX + n4);
    const float* wp = Wf + co * 3 * CO_;
    float4 acc;
    acc.x = acc.y = acc.z = acc.w = bfb[co];
#pragma unroll 8
    for (int cc = 0; cc < CO_; ++cc) {
        float4 fv = fp[cc * (NPIX / 4)];
        float w = wp[cc];
        acc.x += w * fv.x; acc.y += w * fv.y; acc.z += w * fv.z; acc.w += w * fv.w;
    }
#pragma unroll 8
    for (int cc = 0; cc < CO_; ++cc) {
        float4 lv = lp[cc * (NPIX / 4)];
        float w = wp[CO_ + cc];
        acc.x += w * lv.x; acc.y += w * lv.y; acc.z += w * lv.z; acc.w += w * lv.w;
    }
#pragma unroll 8
    for (int cc = 0; cc < CO_; ++cc) {
        float4 av = ap[cc * (NPIX / 4)];
        float w = wp[2 * CO_ + cc];
        acc.x += w * av.x; acc.y += w * av.y; acc.z += w * av.z; acc.w += w * av.w;
    }
    float sc = rsqrtf(v[co] + EPS_) * g[co];
    float sh = bb[co] - m[co] * sc;
    float4 r;
    r.x = fmaxf(acc.x * sc + sh, 0.f);
    r.y = fmaxf(acc.y * sc + sh, 0.f);
    r.z = fmaxf(acc.z * sc + sh, 0.f);
    r.w = fmaxf(acc.w * sc + sh, 0.f);
    const float4* xp = (const float4*)(x + (size_t)b * CI_ * NPIX + n4);
    const float* wr = Wr + co * CI_;
    float4 rr;
    rr.x = rr.y = rr.z = rr.w = 0.f;
#pragma unroll 8
    for (int ci = 0; ci < CI_; ++ci) {
        float4 xv = xp[ci * (NPIX / 4)];
        float w = wr[ci];
        rr.x += w * xv.x; rr.y += w * xv.y; rr.z += w * xv.z; rr.w += w * xv.w;
    }
    float rsv = rsp[0];
    r.x += rsv * rr.x; r.y += rsv * rr.y; r.z += rsv * rr.z; r.w += rsv * rr.w;
    *(float4*)(out + ((size_t)b * CO_ + co) * NPIX + n4) = r;
}

extern "C" void kernel_launch(void* const* d_in, const int* in_sizes, int n_in,
                              void* d_out, int out_size, void* d_ws, size_t ws_size,
                              hipStream_t stream) {
    const float* x   = (const float*)d_in[0];
    const float* W3  = (const float*)d_in[1];
    const float* b3  = (const float*)d_in[2];
    const float* g1  = (const float*)d_in[3];
    const float* b1  = (const float*)d_in[4];
    const float* m1  = (const float*)d_in[5];
    const float* v1  = (const float*)d_in[6];
    const float* Wa  = (const float*)d_in[7];
    const float* ba  = (const float*)d_in[8];
    const float* g2  = (const float*)d_in[9];
    const float* b2  = (const float*)d_in[10];
    const float* m2  = (const float*)d_in[11];
    const float* v2  = (const float*)d_in[12];
    const float* Wq  = (const float*)d_in[13];
    const float* bq  = (const float*)d_in[14];
    const float* Wk  = (const float*)d_in[15];
    const float* bk  = (const float*)d_in[16];
    const float* Wv  = (const float*)d_in[17];
    const float* bv  = (const float*)d_in[18];
    const float* gam = (const float*)d_in[19];
    const float* Wg  = (const float*)d_in[20];
    const float* bg  = (const float*)d_in[21];
    const float* g3  = (const float*)d_in[22];
    const float* b3n = (const float*)d_in[23];
    const float* m3  = (const float*)d_in[24];
    const float* v3  = (const float*)d_in[25];
    const float* Wf  = (const float*)d_in[26];
    const float* bfb = (const float*)d_in[27];
    const float* g4  = (const float*)d_in[28];
    const float* b4  = (const float*)d_in[29];
    const float* m4  = (const float*)d_in[30];
    const float* v4  = (const float*)d_in[31];
    const float* Wr  = (const float*)d_in[32];
    const float* rs  = (const float*)d_in[33];

    float* ws    = (float*)d_ws;
    float* a_    = ws;                  // [0, 2M) floats; fused overwrites after attn
    float* local = ws + 2097152;        // [2M, 4M)
    float* attn  = ws + 4194304;        // [4M, 6M)
    __bf16* V2   = (__bf16*)(ws + 6291456); // [6M, 7M) floats = 4MB bf16
    float* q     = ws + 7340032;        // 262,144
    float* kk    = ws + 7602176;        // 262,144  -> total 30 MiB
    float* fused = a_;                  // alias: a dead after z_attn3

    float* out = (float*)d_out;

    z_proj_a4<<<2048, 256, 0, stream>>>(x, Wa, ba, g2, b2, m2, v2, a_);
    z_projqk<<<1024, 256, 0, stream>>>(a_, Wq, bq, q);
    z_projqk<<<1024, 256, 0, stream>>>(a_, Wk, bk, kk);
    z_projv2<<<1024, 256, 0, stream>>>(a_, Wv, bv, V2);
    z_attn3<<<1024, 256, 0, stream>>>(q, kk, V2, a_, gam, attn);
    z_conv3t<<<512, 256, 0, stream>>>(x, W3, b3, g1, b1, m1, v1, local);
    z_gate4<<<2048, 256, 0, stream>>>(local, attn, Wg, bg, g3, b3n, m3, v3, fused);
    z_out4<<<2048, 256, 0, stream>>>(fused, local, attn, x, Wf, bfb, g4, b4, m4, v4, Wr, rs, out);
}

// Round 10
// 352.575 us; speedup vs baseline: 9.4245x; 1.6221x over previous
//
#include <hip/hip_runtime.h>
#include <hip/hip_bf16.h>

#define CI_ 64
#define CO_ 128
#define NPIX 4096
#define CQ_ 16
#define QT 16
#define MT 256
#define EPS_ 1e-5f

typedef __attribute__((ext_vector_type(8))) __bf16 bf16x8;
typedef __attribute__((ext_vector_type(4))) float f32x4;

// a = relu(bn2(Wa @ x + ba)), 4 outputs per thread along n
__global__ __launch_bounds__(256) void z_proj_a4(
    const float* __restrict__ x, const float* __restrict__ Wa, const float* __restrict__ ba,
    const float* __restrict__ g, const float* __restrict__ bb,
    const float* __restrict__ m, const float* __restrict__ v, float* __restrict__ a)
{
    int i = blockIdx.x * 256 + threadIdx.x;   // B*CO*1024
    int n4 = (i & 1023) * 4;
    int co = (i >> 10) & (CO_ - 1);
    int b = i >> 17;
    const float4* xp = (const float4*)(x + (size_t)b * CI_ * NPIX + n4);
    const float* wp = Wa + co * CI_;
    float4 acc;
    acc.x = acc.y = acc.z = acc.w = ba[co];
#pragma unroll 8
    for (int ci = 0; ci < CI_; ++ci) {
        float4 xv = xp[ci * (NPIX / 4)];
        float w = wp[ci];
        acc.x += w * xv.x; acc.y += w * xv.y; acc.z += w * xv.z; acc.w += w * xv.w;
    }
    float sc = rsqrtf(v[co] + EPS_) * g[co];
    float sh = bb[co] - m[co] * sc;
    float4 r;
    r.x = fmaxf(acc.x * sc + sh, 0.f);
    r.y = fmaxf(acc.y * sc + sh, 0.f);
    r.z = fmaxf(acc.z * sc + sh, 0.f);
    r.w = fmaxf(acc.w * sc + sh, 0.f);
    *(float4*)(a + ((size_t)b * CO_ + co) * NPIX + n4) = r;
}

// LDS-tiled conv3x3 + BN + ReLU, 4-row strips for occupancy.
// grid: b(4) x co-group(16 of 8) x h-strip(16 of 4) = 1024 blocks.
__global__ __launch_bounds__(256) void z_conv3t4(
    const float* __restrict__ x, const float* __restrict__ W3, const float* __restrict__ b3,
    const float* __restrict__ g, const float* __restrict__ bb,
    const float* __restrict__ m, const float* __restrict__ v, float* __restrict__ local)
{
    __shared__ float xs[8][6][66];    // 12.7 KB
    __shared__ float wsm[8][8][9];    // 2.3 KB

    int blk = blockIdx.x;
    int b  = blk >> 8;
    int cg = (blk >> 4) & 15;
    int hs = blk & 15;
    int co0 = cg * 8, h0 = hs * 4;

    int tid = threadIdx.x;
    int w = tid & 63;
    int cl = tid >> 6;
    int coA = co0 + 2 * cl, coB = coA + 1;

    float acc[2][4];
#pragma unroll
    for (int hh = 0; hh < 4; ++hh) { acc[0][hh] = b3[coA]; acc[1][hh] = b3[coB]; }

    for (int ci0 = 0; ci0 < CI_; ci0 += 8) {
        for (int l = tid; l < 8 * 6 * 66; l += 256) {
            int ci = l / 396;
            int rem = l - ci * 396;
            int r = rem / 66;
            int col = rem - r * 66;
            int hh = h0 + r - 1;
            int wg = col - 1;
            float val = 0.f;
            if ((unsigned)hh < 64u && (unsigned)wg < 64u)
                val = x[((size_t)b * CI_ + ci0 + ci) * NPIX + hh * 64 + wg];
            xs[ci][r][col] = val;
        }
        for (int l = tid; l < 8 * 8 * 9; l += 256) {
            int co = l / 72;
            int rem = l - co * 72;
            int ci = rem / 9;
            int tap = rem - ci * 9;
            wsm[co][ci][tap] = W3[((size_t)(co0 + co) * CI_ + ci0 + ci) * 9 + tap];
        }
        __syncthreads();

#pragma unroll
        for (int ci = 0; ci < 8; ++ci) {
            float x0[6], x1[6], x2[6];
#pragma unroll
            for (int r = 0; r < 6; ++r) {
                x0[r] = xs[ci][r][w];
                x1[r] = xs[ci][r][w + 1];
                x2[r] = xs[ci][r][w + 2];
            }
#pragma unroll
            for (int cc = 0; cc < 2; ++cc) {
                const float* wt = &wsm[2 * cl + cc][ci][0];
                float w00 = wt[0], w01 = wt[1], w02 = wt[2];
                float w10 = wt[3], w11 = wt[4], w12 = wt[5];
                float w20 = wt[6], w21 = wt[7], w22 = wt[8];
#pragma unroll
                for (int hh = 0; hh < 4; ++hh) {
                    float s = acc[cc][hh];
                    s += w00 * x0[hh]     + w01 * x1[hh]     + w02 * x2[hh];
                    s += w10 * x0[hh + 1] + w11 * x1[hh + 1] + w12 * x2[hh + 1];
                    s += w20 * x0[hh + 2] + w21 * x1[hh + 2] + w22 * x2[hh + 2];
                    acc[cc][hh] = s;
                }
            }
        }
        __syncthreads();
    }

#pragma unroll
    for (int cc = 0; cc < 2; ++cc) {
        int co = coA + cc;
        float sc = rsqrtf(v[co] + EPS_) * g[co];
        float sh = bb[co] - m[co] * sc;
#pragma unroll
        for (int hh = 0; hh < 4; ++hh) {
            float y = fmaxf(acc[cc][hh] * sc + sh, 0.f);
            local[((size_t)b * CO_ + co) * NPIX + (h0 + hh) * 64 + w] = y;
        }
    }
}

// q/k projection (Cout=16)
__global__ __launch_bounds__(256) void z_projqk(
    const float* __restrict__ a, const float* __restrict__ W, const float* __restrict__ bias,
    float* __restrict__ out)
{
    int i = blockIdx.x * 256 + threadIdx.x;
    int n = i & (NPIX - 1);
    int c = (i >> 12) & (CQ_ - 1);
    int b = i >> 16;
    const float* ap = a + (size_t)b * CO_ * NPIX + n;
    const float* wp = W + c * CO_;
    float acc = bias[c];
#pragma unroll 8
    for (int t = 0; t < CO_; ++t) acc += wp[t] * ap[t * NPIX];
    out[i] = acc;
}

// V2[b][n/8][c][8] bf16 = Wv @ a + bv  (pre-swizzled for MFMA B-fragments)
__global__ __launch_bounds__(256) void z_projv2(
    const float* __restrict__ a, const float* __restrict__ Wv, const float* __restrict__ bv,
    __bf16* __restrict__ V2)
{
    __shared__ __bf16 wsm[128 * 130];
    int tid = threadIdx.x;
    int blk = blockIdx.x;
    int b = blk >> 8;
    int ng = blk & 255;

    for (int i = tid; i < 128 * 128; i += 256) {
        int c = i >> 7, t = i & 127;
        wsm[c * 130 + t] = (__bf16)Wv[i];
    }
    __syncthreads();

    int c = tid & 127;
    int n8 = ng * 2 + (tid >> 7);
    float acc[8];
    float bvc = bv[c];
#pragma unroll
    for (int j = 0; j < 8; ++j) acc[j] = bvc;

    const float4* a4 = (const float4*)(a + (size_t)b * CO_ * NPIX);
#pragma unroll 4
    for (int t = 0; t < 128; ++t) {
        float w = (float)wsm[c * 130 + t];
        float4 a0 = a4[t * 1024 + n8 * 2];
        float4 a1 = a4[t * 1024 + n8 * 2 + 1];
        acc[0] += w * a0.x; acc[1] += w * a0.y; acc[2] += w * a0.z; acc[3] += w * a0.w;
        acc[4] += w * a1.x; acc[5] += w * a1.y; acc[6] += w * a1.z; acc[7] += w * a1.w;
    }
    bf16x8 r;
#pragma unroll
    for (int j = 0; j < 8; ++j) r[j] = (__bf16)acc[j];
    ((bf16x8*)V2)[(size_t)b * 65536 + n8 * 128 + c] = r;
}

// flash attention with MFMA PV (unchanged from round 9)
__global__ __launch_bounds__(256) void z_attn3(
    const float* __restrict__ q, const float* __restrict__ k, const __bf16* __restrict__ V2,
    const float* __restrict__ a, const float* __restrict__ gamp, float* __restrict__ attn)
{
    __shared__ float qs[QT][CQ_];
    __shared__ __align__(16) float s_lds[16 * 260];
    __shared__ __align__(16) __bf16 p_lds[16 * 264];
    __shared__ float rmax[16], rsum[16], rff[16], rnm[16];

    int tid = threadIdx.x;
    int b = blockIdx.x >> 8;
    int q0 = (blockIdx.x & 255) * QT;
    int l = tid & 63;
    int w = tid >> 6;
    int arow = l & 15;
    int agrp = l >> 4;

    if (tid < QT * CQ_) {
        int qi = tid >> 4, c = tid & 15;
        qs[qi][c] = q[((size_t)b * CQ_ + c) * NPIX + q0 + qi];
    }
    if (tid < 16) { rmax[tid] = -1e30f; rsum[tid] = 0.f; }

    f32x4 acc0 = {0.f, 0.f, 0.f, 0.f};
    f32x4 acc1 = {0.f, 0.f, 0.f, 0.f};
    int c0 = w * 32 + (l & 15);
    int c1 = c0 + 16;
    const bf16x8* vbase = (const bf16x8*)V2 + (size_t)b * 65536;

    __syncthreads();

    for (int t = 0; t < NPIX / MT; ++t) {
        int m0 = t * MT;
        float kv[CQ_];
#pragma unroll
        for (int cc = 0; cc < CQ_; ++cc) kv[cc] = k[((size_t)b * CQ_ + cc) * NPIX + m0 + tid];
        float s[QT];
#pragma unroll
        for (int qi = 0; qi < QT; ++qi) {
            float acc = 0.f;
#pragma unroll
            for (int cc = 0; cc < CQ_; ++cc) acc += qs[qi][cc] * kv[cc];
            s[qi] = acc;
            s_lds[qi * 260 + tid] = acc;
        }
        __syncthreads();
        {
            int gq = tid >> 4, j = tid & 15;
            float mx = -1e30f;
#pragma unroll
            for (int i2 = 0; i2 < 16; ++i2) mx = fmaxf(mx, s_lds[gq * 260 + j + 16 * i2]);
#pragma unroll
            for (int off = 8; off; off >>= 1) mx = fmaxf(mx, __shfl_xor(mx, off, 16));
            if (j == 0) {
                float om = rmax[gq];
                float nm = fmaxf(om, mx);
                rff[gq] = __expf(om - nm);
                rnm[gq] = nm;
                rmax[gq] = nm;
            }
        }
        __syncthreads();
#pragma unroll
        for (int qi = 0; qi < QT; ++qi)
            p_lds[qi * 264 + tid] = (__bf16)__expf(s[qi] - rnm[qi]);
        __syncthreads();
        {
            int gq = tid >> 4, j = tid & 15;
            float sm = 0.f;
#pragma unroll
            for (int i2 = 0; i2 < 16; ++i2) sm += (float)p_lds[gq * 264 + j + 16 * i2];
#pragma unroll
            for (int off = 8; off; off >>= 1) sm += __shfl_xor(sm, off, 16);
            if (j == 0) rsum[gq] = rsum[gq] * rff[gq] + sm;
        }
        {
            float rf0 = rff[agrp * 4 + 0];
            float rf1 = rff[agrp * 4 + 1];
            float rf2 = rff[agrp * 4 + 2];
            float rf3 = rff[agrp * 4 + 3];
            acc0[0] *= rf0; acc0[1] *= rf1; acc0[2] *= rf2; acc0[3] *= rf3;
            acc1[0] *= rf0; acc1[1] *= rf1; acc1[2] *= rf2; acc1[3] *= rf3;
#pragma unroll
            for (int ks = 0; ks < 8; ++ks) {
                bf16x8 afrag = *(const bf16x8*)&p_lds[arow * 264 + ks * 32 + agrp * 8];
                int ms = (m0 >> 3) + ks * 4 + agrp;
                bf16x8 bf0 = vbase[ms * 128 + c0];
                bf16x8 bf1 = vbase[ms * 128 + c1];
                acc0 = __builtin_amdgcn_mfma_f32_16x16x32_bf16(afrag, bf0, acc0, 0, 0, 0);
                acc1 = __builtin_amdgcn_mfma_f32_16x16x32_bf16(afrag, bf1, acc1, 0, 0, 0);
            }
        }
        __syncthreads();
    }

    float* o_lds = s_lds;
#pragma unroll
    for (int r = 0; r < 4; ++r) {
        int qrow = agrp * 4 + r;
        o_lds[c0 * 17 + qrow] = acc0[r];
        o_lds[c1 * 17 + qrow] = acc1[r];
    }
    __syncthreads();
    float gam = gamp[0];
    int qi = tid & 15;
    float inv = 1.f / rsum[qi];
#pragma unroll
    for (int j = 0; j < 8; ++j) {
        int cc = (tid >> 4) + 16 * j;
        size_t idx = ((size_t)b * CO_ + cc) * NPIX + q0 + qi;
        attn[idx] = gam * (o_lds[cc * 17 + qi] * inv) + a[idx];
    }
}

// fused gate + final: block = (b, 32-col n-tile); LDS-staged activations.
// thread = 4 co x 4 n.
__global__ __launch_bounds__(256) void z_fuseout(
    const float* __restrict__ local, const float* __restrict__ attn,
    const float* __restrict__ x,
    const float* __restrict__ Wg, const float* __restrict__ bg,
    const float* __restrict__ g3, const float* __restrict__ b3n,
    const float* __restrict__ m3, const float* __restrict__ v3,
    const float* __restrict__ Wf, const float* __restrict__ bfb,
    const float* __restrict__ g4, const float* __restrict__ b4,
    const float* __restrict__ m4, const float* __restrict__ v4,
    const float* __restrict__ Wr, const float* __restrict__ rsp,
    float* __restrict__ out)
{
    __shared__ float sl[128][32];
    __shared__ float sa[128][32];
    __shared__ float sf[128][32];
    __shared__ float sx[64][32];

    int tid = threadIdx.x;
    int b = blockIdx.x >> 7;
    int n0 = (blockIdx.x & 127) * 32;

    // stage local/attn (1024 float4) and x (512 float4)
    for (int l = tid; l < 1024; l += 256) {
        int c = l >> 3, j = l & 7;
        *(float4*)&sl[c][j * 4] = ((const float4*)(local + ((size_t)b * CO_ + c) * NPIX + n0))[j];
        *(float4*)&sa[c][j * 4] = ((const float4*)(attn  + ((size_t)b * CO_ + c) * NPIX + n0))[j];
    }
    for (int l = tid; l < 512; l += 256) {
        int c = l >> 3, j = l & 7;
        *(float4*)&sx[c][j * 4] = ((const float4*)(x + ((size_t)b * CI_ + c) * NPIX + n0))[j];
    }
    __syncthreads();

    int co0 = (tid >> 3) * 4;         // 0..124
    int nn = (tid & 7) * 4;           // 0..28

    // ---- phase 1: gate -> fused into sf ----
    {
        float4 acc[4];
#pragma unroll
        for (int cc = 0; cc < 4; ++cc) {
            float bv = bg[co0 + cc];
            acc[cc].x = bv; acc[cc].y = bv; acc[cc].z = bv; acc[cc].w = bv;
        }
#pragma unroll 4
        for (int k = 0; k < 128; ++k) {
            float4 av = *(float4*)&sl[k][nn];
#pragma unroll
            for (int cc = 0; cc < 4; ++cc) {
                float w = Wg[(size_t)(co0 + cc) * 256 + k];
                acc[cc].x += w * av.x; acc[cc].y += w * av.y; acc[cc].z += w * av.z; acc[cc].w += w * av.w;
            }
        }
#pragma unroll 4
        for (int k = 0; k < 128; ++k) {
            float4 av = *(float4*)&sa[k][nn];
#pragma unroll
            for (int cc = 0; cc < 4; ++cc) {
                float w = Wg[(size_t)(co0 + cc) * 256 + 128 + k];
                acc[cc].x += w * av.x; acc[cc].y += w * av.y; acc[cc].z += w * av.z; acc[cc].w += w * av.w;
            }
        }
#pragma unroll
        for (int cc = 0; cc < 4; ++cc) {
            int co = co0 + cc;
            float sc = rsqrtf(v3[co] + EPS_) * g3[co];
            float sh = b3n[co] - m3[co] * sc;
            float4 lv = *(float4*)&sl[co][nn];
            float4 av = *(float4*)&sa[co][nn];
            float4 r;
            float gx = 1.f / (1.f + __expf(-(acc[cc].x * sc + sh)));
            float gy = 1.f / (1.f + __expf(-(acc[cc].y * sc + sh)));
            float gz = 1.f / (1.f + __expf(-(acc[cc].z * sc + sh)));
            float gw = 1.f / (1.f + __expf(-(acc[cc].w * sc + sh)));
            r.x = gx * lv.x + (1.f - gx) * av.x;
            r.y = gy * lv.y + (1.f - gy) * av.y;
            r.z = gz * lv.z + (1.f - gz) * av.z;
            r.w = gw * lv.w + (1.f - gw) * av.w;
            *(float4*)&sf[co][nn] = r;
        }
    }
    __syncthreads();

    // ---- phase 2: out = relu(bn4(Wf @ [sf; sl; sa])) + rs * (Wr @ sx) ----
    {
        float4 acc[4];
#pragma unroll
        for (int cc = 0; cc < 4; ++cc) {
            float bv = bfb[co0 + cc];
            acc[cc].x = bv; acc[cc].y = bv; acc[cc].z = bv; acc[cc].w = bv;
        }
#pragma unroll 4
        for (int k = 0; k < 128; ++k) {
            float4 av = *(float4*)&sf[k][nn];
#pragma unroll
            for (int cc = 0; cc < 4; ++cc) {
                float w = Wf[(size_t)(co0 + cc) * 384 + k];
                acc[cc].x += w * av.x; acc[cc].y += w * av.y; acc[cc].z += w * av.z; acc[cc].w += w * av.w;
            }
        }
#pragma unroll 4
        for (int k = 0; k < 128; ++k) {
            float4 av = *(float4*)&sl[k][nn];
#pragma unroll
            for (int cc = 0; cc < 4; ++cc) {
                float w = Wf[(size_t)(co0 + cc) * 384 + 128 + k];
                acc[cc].x += w * av.x; acc[cc].y += w * av.y; acc[cc].z += w * av.z; acc[cc].w += w * av.w;
            }
        }
#pragma unroll 4
        for (int k = 0; k < 128; ++k) {
            float4 av = *(float4*)&sa[k][nn];
#pragma unroll
            for (int cc = 0; cc < 4; ++cc) {
                float w = Wf[(size_t)(co0 + cc) * 384 + 256 + k];
                acc[cc].x += w * av.x; acc[cc].y += w * av.y; acc[cc].z += w * av.z; acc[cc].w += w * av.w;
            }
        }
        float4 rr[4];
#pragma unroll
        for (int cc = 0; cc < 4; ++cc) { rr[cc].x = 0.f; rr[cc].y = 0.f; rr[cc].z = 0.f; rr[cc].w = 0.f; }
#pragma unroll 4
        for (int k = 0; k < 64; ++k) {
            float4 av = *(float4*)&sx[k][nn];
#pragma unroll
            for (int cc = 0; cc < 4; ++cc) {
                float w = Wr[(size_t)(co0 + cc) * 64 + k];
                rr[cc].x += w * av.x; rr[cc].y += w * av.y; rr[cc].z += w * av.z; rr[cc].w += w * av.w;
            }
        }
        float rsv = rsp[0];
#pragma unroll
        for (int cc = 0; cc < 4; ++cc) {
            int co = co0 + cc;
            float sc = rsqrtf(v4[co] + EPS_) * g4[co];
            float sh = b4[co] - m4[co] * sc;
            float4 r;
            r.x = fmaxf(acc[cc].x * sc + sh, 0.f) + rsv * rr[cc].x;
            r.y = fmaxf(acc[cc].y * sc + sh, 0.f) + rsv * rr[cc].y;
            r.z = fmaxf(acc[cc].z * sc + sh, 0.f) + rsv * rr[cc].z;
            r.w = fmaxf(acc[cc].w * sc + sh, 0.f) + rsv * rr[cc].w;
            *(float4*)(out + ((size_t)b * CO_ + co) * NPIX + n0 + nn) = r;
        }
    }
}

extern "C" void kernel_launch(void* const* d_in, const int* in_sizes, int n_in,
                              void* d_out, int out_size, void* d_ws, size_t ws_size,
                              hipStream_t stream) {
    const float* x   = (const float*)d_in[0];
    const float* W3  = (const float*)d_in[1];
    const float* b3  = (const float*)d_in[2];
    const float* g1  = (const float*)d_in[3];
    const float* b1  = (const float*)d_in[4];
    const float* m1  = (const float*)d_in[5];
    const float* v1  = (const float*)d_in[6];
    const float* Wa  = (const float*)d_in[7];
    const float* ba  = (const float*)d_in[8];
    const float* g2  = (const float*)d_in[9];
    const float* b2  = (const float*)d_in[10];
    const float* m2  = (const float*)d_in[11];
    const float* v2  = (const float*)d_in[12];
    const float* Wq  = (const float*)d_in[13];
    const float* bq  = (const float*)d_in[14];
    const float* Wk  = (const float*)d_in[15];
    const float* bk  = (const float*)d_in[16];
    const float* Wv  = (const float*)d_in[17];
    const float* bv  = (const float*)d_in[18];
    const float* gam = (const float*)d_in[19];
    const float* Wg  = (const float*)d_in[20];
    const float* bg  = (const float*)d_in[21];
    const float* g3  = (const float*)d_in[22];
    const float* b3n = (const float*)d_in[23];
    const float* m3  = (const float*)d_in[24];
    const float* v3  = (const float*)d_in[25];
    const float* Wf  = (const float*)d_in[26];
    const float* bfb = (const float*)d_in[27];
    const float* g4  = (const float*)d_in[28];
    const float* b4  = (const float*)d_in[29];
    const float* m4  = (const float*)d_in[30];
    const float* v4  = (const float*)d_in[31];
    const float* Wr  = (const float*)d_in[32];
    const float* rs  = (const float*)d_in[33];

    float* ws    = (float*)d_ws;
    float* a_    = ws;                  // [0, 2M)
    float* local = ws + 2097152;        // [2M, 4M)
    float* attn  = ws + 4194304;        // [4M, 6M)
    __bf16* V2   = (__bf16*)(ws + 6291456); // 4MB bf16
    float* q     = ws + 7340032;
    float* kk    = ws + 7602176;        // total 30 MiB

    float* out = (float*)d_out;

    z_proj_a4<<<2048, 256, 0, stream>>>(x, Wa, ba, g2, b2, m2, v2, a_);
    z_projqk<<<1024, 256, 0, stream>>>(a_, Wq, bq, q);
    z_projqk<<<1024, 256, 0, stream>>>(a_, Wk, bk, kk);
    z_projv2<<<1024, 256, 0, stream>>>(a_, Wv, bv, V2);
    z_attn3<<<1024, 256, 0, stream>>>(q, kk, V2, a_, gam, attn);
    z_conv3t4<<<1024, 256, 0, stream>>>(x, W3, b3, g1, b1, m1, v1, local);
    z_fuseout<<<512, 256, 0, stream>>>(local, attn, x, Wg, bg, g3, b3n, m3, v3,
                                       Wf, bfb, g4, b4, m4, v4, Wr, rs, out);
}

// Round 11
// 249.599 us; speedup vs baseline: 13.3128x; 1.4126x over previous
//
#include <hip/hip_runtime.h>
#include <hip/hip_bf16.h>

#define CI_ 64
#define CO_ 128
#define NPIX 4096
#define CQ_ 16
#define QT 16
#define MT 256
#define EPS_ 1e-5f

typedef __attribute__((ext_vector_type(8))) __bf16 bf16x8;
typedef __attribute__((ext_vector_type(4))) float f32x4;

// a = relu(bn2(Wa @ x + ba)), 4 outputs per thread along n
__global__ __launch_bounds__(256) void z_proj_a4(
    const float* __restrict__ x, const float* __restrict__ Wa, const float* __restrict__ ba,
    const float* __restrict__ g, const float* __restrict__ bb,
    const float* __restrict__ m, const float* __restrict__ v, float* __restrict__ a)
{
    int i = blockIdx.x * 256 + threadIdx.x;   // B*CO*1024
    int n4 = (i & 1023) * 4;
    int co = (i >> 10) & (CO_ - 1);
    int b = i >> 17;
    const float4* xp = (const float4*)(x + (size_t)b * CI_ * NPIX + n4);
    const float* wp = Wa + co * CI_;
    float4 acc;
    acc.x = acc.y = acc.z = acc.w = ba[co];
#pragma unroll 8
    for (int ci = 0; ci < CI_; ++ci) {
        float4 xv = xp[ci * (NPIX / 4)];
        float w = wp[ci];
        acc.x += w * xv.x; acc.y += w * xv.y; acc.z += w * xv.z; acc.w += w * xv.w;
    }
    float sc = rsqrtf(v[co] + EPS_) * g[co];
    float sh = bb[co] - m[co] * sc;
    float4 r;
    r.x = fmaxf(acc.x * sc + sh, 0.f);
    r.y = fmaxf(acc.y * sc + sh, 0.f);
    r.z = fmaxf(acc.z * sc + sh, 0.f);
    r.w = fmaxf(acc.w * sc + sh, 0.f);
    *(float4*)(a + ((size_t)b * CO_ + co) * NPIX + n4) = r;
}

// transpose x -> xT[b][n][ci] bf16 (for conv MFMA B-fragments)
__global__ __launch_bounds__(256) void z_prepx(
    const float* __restrict__ x, __bf16* __restrict__ xT)
{
    __shared__ float tl[64][65];
    int b = blockIdx.x >> 6;
    int n0 = (blockIdx.x & 63) * 64;
    int tid = threadIdx.x;
    int nn = tid & 63, c4 = tid >> 6;
#pragma unroll
    for (int p = 0; p < 16; ++p) {
        int ci = p * 4 + c4;
        tl[ci][nn] = x[((size_t)b * CI_ + ci) * NPIX + n0 + nn];
    }
    __syncthreads();
#pragma unroll
    for (int p = 0; p < 2; ++p) {
        int idx = p * 256 + tid;
        int n = idx >> 3, cig = idx & 7;
        bf16x8 vv;
#pragma unroll
        for (int j = 0; j < 8; ++j) vv[j] = (__bf16)tl[cig * 8 + j][n];
        ((bf16x8*)xT)[((size_t)b * NPIX + n0 + n) * 8 + cig] = vv;
    }
}

// W3[co][ci][tap] fp32 -> Wt2[co][tap*64+ci] bf16
__global__ __launch_bounds__(256) void z_prepw(
    const float* __restrict__ W3, __bf16* __restrict__ Wt2)
{
    int o = blockIdx.x * 256 + threadIdx.x;   // 128*576 = 73728
    int co = o / 576;
    int r = o - co * 576;
    int tap = r >> 6;
    int ci = r & 63;
    Wt2[o] = (__bf16)W3[((size_t)co * CI_ + ci) * 9 + tap];
}

// MFMA implicit-GEMM conv3x3 + BN + ReLU.
// grid: b(4) x h(64) x cogroup(4 of 32) = 1024 blocks, 256 thr (4 waves = 4 n-tiles).
__global__ __launch_bounds__(256) void z_conv3m(
    const __bf16* __restrict__ xT, const __bf16* __restrict__ Wt2,
    const float* __restrict__ b3, const float* __restrict__ g,
    const float* __restrict__ bb, const float* __restrict__ m,
    const float* __restrict__ v, float* __restrict__ local)
{
    __shared__ __align__(16) __bf16 xt[3 * 66 * 64];   // 25344 B, ci-chunk XOR-swizzled by col
    __shared__ __align__(16) __bf16 wt[32 * 576];      // 36864 B, k-chunk XOR-swizzled by co
    __shared__ float scs[32], shs[32];

    int blk = blockIdx.x;
    int b = blk >> 8;
    int h = (blk >> 2) & 63;
    int cg = blk & 3;
    int co0 = cg * 32;
    int tid = threadIdx.x;
    int l = tid & 63;
    int nt = tid >> 6;               // wave id = n-tile
    int lm = l & 15, lh = l >> 4;

    if (tid < 32) {
        int co = co0 + tid;
        float scv = rsqrtf(v[co] + EPS_) * g[co];
        scs[tid] = scv;
        shs[tid] = (b3[co] - m[co]) * scv + bb[co];
    }

    // stage x halo tile: 3 rows x 66 cols x 8 ci-chunks
    const bf16x8* xs = (const bf16x8*)xT + (size_t)b * (NPIX * 8);
    for (int i = tid; i < 1584; i += 256) {
        int r = i / 528;
        int rem = i - r * 528;
        int c = rem >> 3;
        int cig = rem & 7;
        int hh = h + r - 1;
        int gc = c - 1;
        bf16x8 val;
#pragma unroll
        for (int j = 0; j < 8; ++j) val[j] = (__bf16)0.f;
        if ((unsigned)hh < 64u && (unsigned)gc < 64u)
            val = xs[(hh * 64 + gc) * 8 + cig];
        *(bf16x8*)&xt[(r * 66 + c) * 64 + ((cig ^ (c & 7)) * 8)] = val;
    }
    // stage W slice: 32 co x 72 k-chunks
    const bf16x8* wsrc = (const bf16x8*)Wt2 + (size_t)co0 * 72;
    for (int i = tid; i < 2304; i += 256) {
        int co = i / 72;
        int kc = i - co * 72;
        *(bf16x8*)&wt[co * 576 + ((kc ^ (co & 7)) * 8)] = wsrc[i];
    }
    __syncthreads();

    f32x4 acc0 = {0.f, 0.f, 0.f, 0.f};
    f32x4 acc1 = {0.f, 0.f, 0.f, 0.f};
#pragma unroll
    for (int tap = 0; tap < 9; ++tap) {
        int dh = tap / 3, dw = tap % 3;
#pragma unroll
        for (int ks = 0; ks < 2; ++ks) {
            int cig = ks * 4 + lh;                 // ci-chunk within row (0..7)
            int col = nt * 16 + lm + dw;           // 0..65
            bf16x8 bfr = *(const bf16x8*)&xt[(dh * 66 + col) * 64 + ((cig ^ (col & 7)) * 8)];
            int kcg = tap * 8 + cig;               // global k-chunk (0..71)
            bf16x8 a0 = *(const bf16x8*)&wt[lm * 576 + ((kcg ^ (lm & 7)) * 8)];
            bf16x8 a1 = *(const bf16x8*)&wt[(16 + lm) * 576 + ((kcg ^ (lm & 7)) * 8)];
            acc0 = __builtin_amdgcn_mfma_f32_16x16x32_bf16(a0, bfr, acc0, 0, 0, 0);
            acc1 = __builtin_amdgcn_mfma_f32_16x16x32_bf16(a1, bfr, acc1, 0, 0, 0);
        }
    }

    size_t obase = (size_t)b * CO_ * NPIX + h * 64 + nt * 16 + lm;
#pragma unroll
    for (int r = 0; r < 4; ++r) {
        int cl0 = lh * 4 + r;
        float y0 = fmaxf(acc0[r] * scs[cl0] + shs[cl0], 0.f);
        local[obase + (size_t)(co0 + cl0) * NPIX] = y0;
        int cl1 = 16 + cl0;
        float y1 = fmaxf(acc1[r] * scs[cl1] + shs[cl1], 0.f);
        local[obase + (size_t)(co0 + cl1) * NPIX] = y1;
    }
}

// q/k projection (Cout=16)
__global__ __launch_bounds__(256) void z_projqk(
    const float* __restrict__ a, const float* __restrict__ W, const float* __restrict__ bias,
    float* __restrict__ out)
{
    int i = blockIdx.x * 256 + threadIdx.x;
    int n = i & (NPIX - 1);
    int c = (i >> 12) & (CQ_ - 1);
    int b = i >> 16;
    const float* ap = a + (size_t)b * CO_ * NPIX + n;
    const float* wp = W + c * CO_;
    float acc = bias[c];
#pragma unroll 8
    for (int t = 0; t < CO_; ++t) acc += wp[t] * ap[t * NPIX];
    out[i] = acc;
}

// V2[b][n/8][c][8] bf16 = Wv @ a + bv  (pre-swizzled for MFMA B-fragments)
__global__ __launch_bounds__(256) void z_projv2(
    const float* __restrict__ a, const float* __restrict__ Wv, const float* __restrict__ bv,
    __bf16* __restrict__ V2)
{
    __shared__ __bf16 wsm[128 * 130];
    int tid = threadIdx.x;
    int blk = blockIdx.x;
    int b = blk >> 8;
    int ng = blk & 255;

    for (int i = tid; i < 128 * 128; i += 256) {
        int c = i >> 7, t = i & 127;
        wsm[c * 130 + t] = (__bf16)Wv[i];
    }
    __syncthreads();

    int c = tid & 127;
    int n8 = ng * 2 + (tid >> 7);
    float acc[8];
    float bvc = bv[c];
#pragma unroll
    for (int j = 0; j < 8; ++j) acc[j] = bvc;

    const float4* a4 = (const float4*)(a + (size_t)b * CO_ * NPIX);
#pragma unroll 4
    for (int t = 0; t < 128; ++t) {
        float w = (float)wsm[c * 130 + t];
        float4 a0 = a4[t * 1024 + n8 * 2];
        float4 a1 = a4[t * 1024 + n8 * 2 + 1];
        acc[0] += w * a0.x; acc[1] += w * a0.y; acc[2] += w * a0.z; acc[3] += w * a0.w;
        acc[4] += w * a1.x; acc[5] += w * a1.y; acc[6] += w * a1.z; acc[7] += w * a1.w;
    }
    bf16x8 r;
#pragma unroll
    for (int j = 0; j < 8; ++j) r[j] = (__bf16)acc[j];
    ((bf16x8*)V2)[(size_t)b * 65536 + n8 * 128 + c] = r;
}

// flash attention with MFMA PV (unchanged, validated)
__global__ __launch_bounds__(256) void z_attn3(
    const float* __restrict__ q, const float* __restrict__ k, const __bf16* __restrict__ V2,
    const float* __restrict__ a, const float* __restrict__ gamp, float* __restrict__ attn)
{
    __shared__ float qs[QT][CQ_];
    __shared__ __align__(16) float s_lds[16 * 260];
    __shared__ __align__(16) __bf16 p_lds[16 * 264];
    __shared__ float rmax[16], rsum[16], rff[16], rnm[16];

    int tid = threadIdx.x;
    int b = blockIdx.x >> 8;
    int q0 = (blockIdx.x & 255) * QT;
    int l = tid & 63;
    int w = tid >> 6;
    int arow = l & 15;
    int agrp = l >> 4;

    if (tid < QT * CQ_) {
        int qi = tid >> 4, c = tid & 15;
        qs[qi][c] = q[((size_t)b * CQ_ + c) * NPIX + q0 + qi];
    }
    if (tid < 16) { rmax[tid] = -1e30f; rsum[tid] = 0.f; }

    f32x4 acc0 = {0.f, 0.f, 0.f, 0.f};
    f32x4 acc1 = {0.f, 0.f, 0.f, 0.f};
    int c0 = w * 32 + (l & 15);
    int c1 = c0 + 16;
    const bf16x8* vbase = (const bf16x8*)V2 + (size_t)b * 65536;

    __syncthreads();

    for (int t = 0; t < NPIX / MT; ++t) {
        int m0 = t * MT;
        float kv[CQ_];
#pragma unroll
        for (int cc = 0; cc < CQ_; ++cc) kv[cc] = k[((size_t)b * CQ_ + cc) * NPIX + m0 + tid];
        float s[QT];
#pragma unroll
        for (int qi = 0; qi < QT; ++qi) {
            float acc = 0.f;
#pragma unroll
            for (int cc = 0; cc < CQ_; ++cc) acc += qs[qi][cc] * kv[cc];
            s[qi] = acc;
            s_lds[qi * 260 + tid] = acc;
        }
        __syncthreads();
        {
            int gq = tid >> 4, j = tid & 15;
            float mx = -1e30f;
#pragma unroll
            for (int i2 = 0; i2 < 16; ++i2) mx = fmaxf(mx, s_lds[gq * 260 + j + 16 * i2]);
#pragma unroll
            for (int off = 8; off; off >>= 1) mx = fmaxf(mx, __shfl_xor(mx, off, 16));
            if (j == 0) {
                float om = rmax[gq];
                float nm = fmaxf(om, mx);
                rff[gq] = __expf(om - nm);
                rnm[gq] = nm;
                rmax[gq] = nm;
            }
        }
        __syncthreads();
#pragma unroll
        for (int qi = 0; qi < QT; ++qi)
            p_lds[qi * 264 + tid] = (__bf16)__expf(s[qi] - rnm[qi]);
        __syncthreads();
        {
            int gq = tid >> 4, j = tid & 15;
            float sm = 0.f;
#pragma unroll
            for (int i2 = 0; i2 < 16; ++i2) sm += (float)p_lds[gq * 264 + j + 16 * i2];
#pragma unroll
            for (int off = 8; off; off >>= 1) sm += __shfl_xor(sm, off, 16);
            if (j == 0) rsum[gq] = rsum[gq] * rff[gq] + sm;
        }
        {
            float rf0 = rff[agrp * 4 + 0];
            float rf1 = rff[agrp * 4 + 1];
            float rf2 = rff[agrp * 4 + 2];
            float rf3 = rff[agrp * 4 + 3];
            acc0[0] *= rf0; acc0[1] *= rf1; acc0[2] *= rf2; acc0[3] *= rf3;
            acc1[0] *= rf0; acc1[1] *= rf1; acc1[2] *= rf2; acc1[3] *= rf3;
#pragma unroll
            for (int ks = 0; ks < 8; ++ks) {
                bf16x8 afrag = *(const bf16x8*)&p_lds[arow * 264 + ks * 32 + agrp * 8];
                int ms = (m0 >> 3) + ks * 4 + agrp;
                bf16x8 bf0 = vbase[ms * 128 + c0];
                bf16x8 bf1 = vbase[ms * 128 + c1];
                acc0 = __builtin_amdgcn_mfma_f32_16x16x32_bf16(afrag, bf0, acc0, 0, 0, 0);
                acc1 = __builtin_amdgcn_mfma_f32_16x16x32_bf16(afrag, bf1, acc1, 0, 0, 0);
            }
        }
        __syncthreads();
    }

    float* o_lds = s_lds;
#pragma unroll
    for (int r = 0; r < 4; ++r) {
        int qrow = agrp * 4 + r;
        o_lds[c0 * 17 + qrow] = acc0[r];
        o_lds[c1 * 17 + qrow] = acc1[r];
    }
    __syncthreads();
    float gam = gamp[0];
    int qi = tid & 15;
    float inv = 1.f / rsum[qi];
#pragma unroll
    for (int j = 0; j < 8; ++j) {
        int cc = (tid >> 4) + 16 * j;
        size_t idx = ((size_t)b * CO_ + cc) * NPIX + q0 + qi;
        attn[idx] = gam * (o_lds[cc * 17 + qi] * inv) + a[idx];
    }
}

// fused gate + final (unchanged)
__global__ __launch_bounds__(256) void z_fuseout(
    const float* __restrict__ local, const float* __restrict__ attn,
    const float* __restrict__ x,
    const float* __restrict__ Wg, const float* __restrict__ bg,
    const float* __restrict__ g3, const float* __restrict__ b3n,
    const float* __restrict__ m3, const float* __restrict__ v3,
    const float* __restrict__ Wf, const float* __restrict__ bfb,
    const float* __restrict__ g4, const float* __restrict__ b4,
    const float* __restrict__ m4, const float* __restrict__ v4,
    const float* __restrict__ Wr, const float* __restrict__ rsp,
    float* __restrict__ out)
{
    __shared__ float sl[128][32];
    __shared__ float sa[128][32];
    __shared__ float sf[128][32];
    __shared__ float sx[64][32];

    int tid = threadIdx.x;
    int b = blockIdx.x >> 7;
    int n0 = (blockIdx.x & 127) * 32;

    for (int l = tid; l < 1024; l += 256) {
        int c = l >> 3, j = l & 7;
        *(float4*)&sl[c][j * 4] = ((const float4*)(local + ((size_t)b * CO_ + c) * NPIX + n0))[j];
        *(float4*)&sa[c][j * 4] = ((const float4*)(attn  + ((size_t)b * CO_ + c) * NPIX + n0))[j];
    }
    for (int l = tid; l < 512; l += 256) {
        int c = l >> 3, j = l & 7;
        *(float4*)&sx[c][j * 4] = ((const float4*)(x + ((size_t)b * CI_ + c) * NPIX + n0))[j];
    }
    __syncthreads();

    int co0 = (tid >> 3) * 4;
    int nn = (tid & 7) * 4;

    {
        float4 acc[4];
#pragma unroll
        for (int cc = 0; cc < 4; ++cc) {
            float bv = bg[co0 + cc];
            acc[cc].x = bv; acc[cc].y = bv; acc[cc].z = bv; acc[cc].w = bv;
        }
#pragma unroll 4
        for (int k = 0; k < 128; ++k) {
            float4 av = *(float4*)&sl[k][nn];
#pragma unroll
            for (int cc = 0; cc < 4; ++cc) {
                float w = Wg[(size_t)(co0 + cc) * 256 + k];
                acc[cc].x += w * av.x; acc[cc].y += w * av.y; acc[cc].z += w * av.z; acc[cc].w += w * av.w;
            }
        }
#pragma unroll 4
        for (int k = 0; k < 128; ++k) {
            float4 av = *(float4*)&sa[k][nn];
#pragma unroll
            for (int cc = 0; cc < 4; ++cc) {
                float w = Wg[(size_t)(co0 + cc) * 256 + 128 + k];
                acc[cc].x += w * av.x; acc[cc].y += w * av.y; acc[cc].z += w * av.z; acc[cc].w += w * av.w;
            }
        }
#pragma unroll
        for (int cc = 0; cc < 4; ++cc) {
            int co = co0 + cc;
            float sc = rsqrtf(v3[co] + EPS_) * g3[co];
            float sh = b3n[co] - m3[co] * sc;
            float4 lv = *(float4*)&sl[co][nn];
            float4 av = *(float4*)&sa[co][nn];
            float4 r;
            float gx = 1.f / (1.f + __expf(-(acc[cc].x * sc + sh)));
            float gy = 1.f / (1.f + __expf(-(acc[cc].y * sc + sh)));
            float gz = 1.f / (1.f + __expf(-(acc[cc].z * sc + sh)));
            float gw = 1.f / (1.f + __expf(-(acc[cc].w * sc + sh)));
            r.x = gx * lv.x + (1.f - gx) * av.x;
            r.y = gy * lv.y + (1.f - gy) * av.y;
            r.z = gz * lv.z + (1.f - gz) * av.z;
            r.w = gw * lv.w + (1.f - gw) * av.w;
            *(float4*)&sf[co][nn] = r;
        }
    }
    __syncthreads();

    {
        float4 acc[4];
#pragma unroll
        for (int cc = 0; cc < 4; ++cc) {
            float bv = bfb[co0 + cc];
            acc[cc].x = bv; acc[cc].y = bv; acc[cc].z = bv; acc[cc].w = bv;
        }
#pragma unroll 4
        for (int k = 0; k < 128; ++k) {
            float4 av = *(float4*)&sf[k][nn];
#pragma unroll
            for (int cc = 0; cc < 4; ++cc) {
                float w = Wf[(size_t)(co0 + cc) * 384 + k];
                acc[cc].x += w * av.x; acc[cc].y += w * av.y; acc[cc].z += w * av.z; acc[cc].w += w * av.w;
            }
        }
#pragma unroll 4
        for (int k = 0; k < 128; ++k) {
            float4 av = *(float4*)&sl[k][nn];
#pragma unroll
            for (int cc = 0; cc < 4; ++cc) {
                float w = Wf[(size_t)(co0 + cc) * 384 + 128 + k];
                acc[cc].x += w * av.x; acc[cc].y += w * av.y; acc[cc].z += w * av.z; acc[cc].w += w * av.w;
            }
        }
#pragma unroll 4
        for (int k = 0; k < 128; ++k) {
            float4 av = *(float4*)&sa[k][nn];
#pragma unroll
            for (int cc = 0; cc < 4; ++cc) {
                float w = Wf[(size_t)(co0 + cc) * 384 + 256 + k];
                acc[cc].x += w * av.x; acc[cc].y += w * av.y; acc[cc].z += w * av.z; acc[cc].w += w * av.w;
            }
        }
        float4 rr[4];
#pragma unroll
        for (int cc = 0; cc < 4; ++cc) { rr[cc].x = 0.f; rr[cc].y = 0.f; rr[cc].z = 0.f; rr[cc].w = 0.f; }
#pragma unroll 4
        for (int k = 0; k < 64; ++k) {
            float4 av = *(float4*)&sx[k][nn];
#pragma unroll
            for (int cc = 0; cc < 4; ++cc) {
                float w = Wr[(size_t)(co0 + cc) * 64 + k];
                rr[cc].x += w * av.x; rr[cc].y += w * av.y; rr[cc].z += w * av.z; rr[cc].w += w * av.w;
            }
        }
        float rsv = rsp[0];
#pragma unroll
        for (int cc = 0; cc < 4; ++cc) {
            int co = co0 + cc;
            float sc = rsqrtf(v4[co] + EPS_) * g4[co];
            float sh = b4[co] - m4[co] * sc;
            float4 r;
            r.x = fmaxf(acc[cc].x * sc + sh, 0.f) + rsv * rr[cc].x;
            r.y = fmaxf(acc[cc].y * sc + sh, 0.f) + rsv * rr[cc].y;
            r.z = fmaxf(acc[cc].z * sc + sh, 0.f) + rsv * rr[cc].z;
            r.w = fmaxf(acc[cc].w * sc + sh, 0.f) + rsv * rr[cc].w;
            *(float4*)(out + ((size_t)b * CO_ + co) * NPIX + n0 + nn) = r;
        }
    }
}

extern "C" void kernel_launch(void* const* d_in, const int* in_sizes, int n_in,
                              void* d_out, int out_size, void* d_ws, size_t ws_size,
                              hipStream_t stream) {
    const float* x   = (const float*)d_in[0];
    const float* W3  = (const float*)d_in[1];
    const float* b3  = (const float*)d_in[2];
    const float* g1  = (const float*)d_in[3];
    const float* b1  = (const float*)d_in[4];
    const float* m1  = (const float*)d_in[5];
    const float* v1  = (const float*)d_in[6];
    const float* Wa  = (const float*)d_in[7];
    const float* ba  = (const float*)d_in[8];
    const float* g2  = (const float*)d_in[9];
    const float* b2  = (const float*)d_in[10];
    const float* m2  = (const float*)d_in[11];
    const float* v2  = (const float*)d_in[12];
    const float* Wq  = (const float*)d_in[13];
    const float* bq  = (const float*)d_in[14];
    const float* Wk  = (const float*)d_in[15];
    const float* bk  = (const float*)d_in[16];
    const float* Wv  = (const float*)d_in[17];
    const float* bv  = (const float*)d_in[18];
    const float* gam = (const float*)d_in[19];
    const float* Wg  = (const float*)d_in[20];
    const float* bg  = (const float*)d_in[21];
    const float* g3  = (const float*)d_in[22];
    const float* b3n = (const float*)d_in[23];
    const float* m3  = (const float*)d_in[24];
    const float* v3  = (const float*)d_in[25];
    const float* Wf  = (const float*)d_in[26];
    const float* bfb = (const float*)d_in[27];
    const float* g4  = (const float*)d_in[28];
    const float* b4  = (const float*)d_in[29];
    const float* m4  = (const float*)d_in[30];
    const float* v4  = (const float*)d_in[31];
    const float* Wr  = (const float*)d_in[32];
    const float* rs  = (const float*)d_in[33];

    float* ws    = (float*)d_ws;
    float* a_    = ws;                       // [0, 2M)
    float* local = ws + 2097152;             // [2M, 4M)
    float* attn  = ws + 4194304;             // [4M, 6M)
    __bf16* V2   = (__bf16*)(ws + 6291456);  // 4 MB bf16
    float* q     = ws + 7340032;             // 262,144
    float* kk    = ws + 7602176;             // 262,144
    __bf16* xT   = (__bf16*)(ws + 7864320);  // 2 MB bf16 (1,048,576 elems)
    __bf16* Wt2  = (__bf16*)(ws + 8388608);  // 147 KB bf16 (73,728 elems)
    // total ≈ 33.7 MiB

    float* out = (float*)d_out;

    z_prepx<<<256, 256, 0, stream>>>(x, xT);
    z_prepw<<<288, 256, 0, stream>>>(W3, Wt2);
    z_proj_a4<<<2048, 256, 0, stream>>>(x, Wa, ba, g2, b2, m2, v2, a_);
    z_projqk<<<1024, 256, 0, stream>>>(a_, Wq, bq, q);
    z_projqk<<<1024, 256, 0, stream>>>(a_, Wk, bk, kk);
    z_projv2<<<1024, 256, 0, stream>>>(a_, Wv, bv, V2);
    z_attn3<<<1024, 256, 0, stream>>>(q, kk, V2, a_, gam, attn);
    z_conv3m<<<1024, 256, 0, stream>>>(xT, Wt2, b3, g1, b1, m1, v1, local);
    z_fuseout<<<512, 256, 0, stream>>>(local, attn, x, Wg, bg, g3, b3n, m3, v3,
                                       Wf, bfb, g4, b4, m4, v4, Wr, rs, out);
}

// Round 12
// 213.188 us; speedup vs baseline: 15.5865x; 1.1708x over previous
//
#include <hip/hip_runtime.h>
#include <hip/hip_bf16.h>

#define CI_ 64
#define CO_ 128
#define NPIX 4096
#define CQ_ 16
#define QT 16
#define MT 256
#define EPS_ 1e-5f

typedef __attribute__((ext_vector_type(8))) __bf16 bf16x8;
typedef __attribute__((ext_vector_type(4))) __bf16 bf16x4;
typedef __attribute__((ext_vector_type(4))) float f32x4;

// a = relu(bn2(Wa @ x + ba)), 4 outputs per thread along n
__global__ __launch_bounds__(256) void z_proj_a4(
    const float* __restrict__ x, const float* __restrict__ Wa, const float* __restrict__ ba,
    const float* __restrict__ g, const float* __restrict__ bb,
    const float* __restrict__ m, const float* __restrict__ v, float* __restrict__ a)
{
    int i = blockIdx.x * 256 + threadIdx.x;   // B*CO*1024
    int n4 = (i & 1023) * 4;
    int co = (i >> 10) & (CO_ - 1);
    int b = i >> 17;
    const float4* xp = (const float4*)(x + (size_t)b * CI_ * NPIX + n4);
    const float* wp = Wa + co * CI_;
    float4 acc;
    acc.x = acc.y = acc.z = acc.w = ba[co];
#pragma unroll 8
    for (int ci = 0; ci < CI_; ++ci) {
        float4 xv = xp[ci * (NPIX / 4)];
        float w = wp[ci];
        acc.x += w * xv.x; acc.y += w * xv.y; acc.z += w * xv.z; acc.w += w * xv.w;
    }
    float sc = rsqrtf(v[co] + EPS_) * g[co];
    float sh = bb[co] - m[co] * sc;
    float4 r;
    r.x = fmaxf(acc.x * sc + sh, 0.f);
    r.y = fmaxf(acc.y * sc + sh, 0.f);
    r.z = fmaxf(acc.z * sc + sh, 0.f);
    r.w = fmaxf(acc.w * sc + sh, 0.f);
    *(float4*)(a + ((size_t)b * CO_ + co) * NPIX + n4) = r;
}

// transpose x -> xT[b][n][ci] bf16 (for conv MFMA B-fragments)
__global__ __launch_bounds__(256) void z_prepx(
    const float* __restrict__ x, __bf16* __restrict__ xT)
{
    __shared__ float tl[64][65];
    int b = blockIdx.x >> 6;
    int n0 = (blockIdx.x & 63) * 64;
    int tid = threadIdx.x;
    int nn = tid & 63, c4 = tid >> 6;
#pragma unroll
    for (int p = 0; p < 16; ++p) {
        int ci = p * 4 + c4;
        tl[ci][nn] = x[((size_t)b * CI_ + ci) * NPIX + n0 + nn];
    }
    __syncthreads();
#pragma unroll
    for (int p = 0; p < 2; ++p) {
        int idx = p * 256 + tid;
        int n = idx >> 3, cig = idx & 7;
        bf16x8 vv;
#pragma unroll
        for (int j = 0; j < 8; ++j) vv[j] = (__bf16)tl[cig * 8 + j][n];
        ((bf16x8*)xT)[((size_t)b * NPIX + n0 + n) * 8 + cig] = vv;
    }
}

// W3[co][ci][tap] fp32 -> Wt2[co][tap*64+ci] bf16
__global__ __launch_bounds__(256) void z_prepw(
    const float* __restrict__ W3, __bf16* __restrict__ Wt2)
{
    int o = blockIdx.x * 256 + threadIdx.x;   // 128*576 = 73728
    int co = o / 576;
    int r = o - co * 576;
    int tap = r >> 6;
    int ci = r & 63;
    Wt2[o] = (__bf16)W3[((size_t)co * CI_ + ci) * 9 + tap];
}

// MFMA implicit-GEMM conv3x3 + BN + ReLU (validated round 11)
__global__ __launch_bounds__(256) void z_conv3m(
    const __bf16* __restrict__ xT, const __bf16* __restrict__ Wt2,
    const float* __restrict__ b3, const float* __restrict__ g,
    const float* __restrict__ bb, const float* __restrict__ m,
    const float* __restrict__ v, float* __restrict__ local)
{
    __shared__ __align__(16) __bf16 xt[3 * 66 * 64];
    __shared__ __align__(16) __bf16 wt[32 * 576];
    __shared__ float scs[32], shs[32];

    int blk = blockIdx.x;
    int b = blk >> 8;
    int h = (blk >> 2) & 63;
    int cg = blk & 3;
    int co0 = cg * 32;
    int tid = threadIdx.x;
    int l = tid & 63;
    int nt = tid >> 6;
    int lm = l & 15, lh = l >> 4;

    if (tid < 32) {
        int co = co0 + tid;
        float scv = rsqrtf(v[co] + EPS_) * g[co];
        scs[tid] = scv;
        shs[tid] = (b3[co] - m[co]) * scv + bb[co];
    }

    const bf16x8* xs = (const bf16x8*)xT + (size_t)b * (NPIX * 8);
    for (int i = tid; i < 1584; i += 256) {
        int r = i / 528;
        int rem = i - r * 528;
        int c = rem >> 3;
        int cig = rem & 7;
        int hh = h + r - 1;
        int gc = c - 1;
        bf16x8 val;
#pragma unroll
        for (int j = 0; j < 8; ++j) val[j] = (__bf16)0.f;
        if ((unsigned)hh < 64u && (unsigned)gc < 64u)
            val = xs[(hh * 64 + gc) * 8 + cig];
        *(bf16x8*)&xt[(r * 66 + c) * 64 + ((cig ^ (c & 7)) * 8)] = val;
    }
    const bf16x8* wsrc = (const bf16x8*)Wt2 + (size_t)co0 * 72;
    for (int i = tid; i < 2304; i += 256) {
        int co = i / 72;
        int kc = i - co * 72;
        *(bf16x8*)&wt[co * 576 + ((kc ^ (co & 7)) * 8)] = wsrc[i];
    }
    __syncthreads();

    f32x4 acc0 = {0.f, 0.f, 0.f, 0.f};
    f32x4 acc1 = {0.f, 0.f, 0.f, 0.f};
#pragma unroll
    for (int tap = 0; tap < 9; ++tap) {
        int dh = tap / 3, dw = tap % 3;
#pragma unroll
        for (int ks = 0; ks < 2; ++ks) {
            int cig = ks * 4 + lh;
            int col = nt * 16 + lm + dw;
            bf16x8 bfr = *(const bf16x8*)&xt[(dh * 66 + col) * 64 + ((cig ^ (col & 7)) * 8)];
            int kcg = tap * 8 + cig;
            bf16x8 a0 = *(const bf16x8*)&wt[lm * 576 + ((kcg ^ (lm & 7)) * 8)];
            bf16x8 a1 = *(const bf16x8*)&wt[(16 + lm) * 576 + ((kcg ^ (lm & 7)) * 8)];
            acc0 = __builtin_amdgcn_mfma_f32_16x16x32_bf16(a0, bfr, acc0, 0, 0, 0);
            acc1 = __builtin_amdgcn_mfma_f32_16x16x32_bf16(a1, bfr, acc1, 0, 0, 0);
        }
    }

    size_t obase = (size_t)b * CO_ * NPIX + h * 64 + nt * 16 + lm;
#pragma unroll
    for (int r = 0; r < 4; ++r) {
        int cl0 = lh * 4 + r;
        float y0 = fmaxf(acc0[r] * scs[cl0] + shs[cl0], 0.f);
        local[obase + (size_t)(co0 + cl0) * NPIX] = y0;
        int cl1 = 16 + cl0;
        float y1 = fmaxf(acc1[r] * scs[cl1] + shs[cl1], 0.f);
        local[obase + (size_t)(co0 + cl1) * NPIX] = y1;
    }
}

// q projection (Cout=16), fp32 [b][c][n]
__global__ __launch_bounds__(256) void z_projqk(
    const float* __restrict__ a, const float* __restrict__ W, const float* __restrict__ bias,
    float* __restrict__ out)
{
    int i = blockIdx.x * 256 + threadIdx.x;
    int n = i & (NPIX - 1);
    int c = (i >> 12) & (CQ_ - 1);
    int b = i >> 16;
    const float* ap = a + (size_t)b * CO_ * NPIX + n;
    const float* wp = W + c * CO_;
    float acc = bias[c];
#pragma unroll 8
    for (int t = 0; t < CO_; ++t) acc += wp[t] * ap[t * NPIX];
    out[i] = acc;
}

// k projection -> transposed bf16 kT[b][n][16]
__global__ __launch_bounds__(256) void z_projkT(
    const float* __restrict__ a, const float* __restrict__ W, const float* __restrict__ bias,
    __bf16* __restrict__ kT)
{
    int i = blockIdx.x * 256 + threadIdx.x;
    int n = i & (NPIX - 1);
    int c = (i >> 12) & (CQ_ - 1);
    int b = i >> 16;
    const float* ap = a + (size_t)b * CO_ * NPIX + n;
    const float* wp = W + c * CO_;
    float acc = bias[c];
#pragma unroll 8
    for (int t = 0; t < CO_; ++t) acc += wp[t] * ap[t * NPIX];
    kT[((size_t)b * NPIX + n) * CQ_ + c] = (__bf16)acc;
}

// V2[b][n/8][c][8] bf16 = Wv @ a + bv  (MFMA B-fragment layout)
__global__ __launch_bounds__(256) void z_projv2(
    const float* __restrict__ a, const float* __restrict__ Wv, const float* __restrict__ bv,
    __bf16* __restrict__ V2)
{
    __shared__ __bf16 wsm[128 * 130];
    int tid = threadIdx.x;
    int blk = blockIdx.x;
    int b = blk >> 8;
    int ng = blk & 255;

    for (int i = tid; i < 128 * 128; i += 256) {
        int c = i >> 7, t = i & 127;
        wsm[c * 130 + t] = (__bf16)Wv[i];
    }
    __syncthreads();

    int c = tid & 127;
    int n8 = ng * 2 + (tid >> 7);
    float acc[8];
    float bvc = bv[c];
#pragma unroll
    for (int j = 0; j < 8; ++j) acc[j] = bvc;

    const float4* a4 = (const float4*)(a + (size_t)b * CO_ * NPIX);
#pragma unroll 4
    for (int t = 0; t < 128; ++t) {
        float w = (float)wsm[c * 130 + t];
        float4 a0 = a4[t * 1024 + n8 * 2];
        float4 a1 = a4[t * 1024 + n8 * 2 + 1];
        acc[0] += w * a0.x; acc[1] += w * a0.y; acc[2] += w * a0.z; acc[3] += w * a0.w;
        acc[4] += w * a1.x; acc[5] += w * a1.y; acc[6] += w * a1.z; acc[7] += w * a1.w;
    }
    bf16x8 r;
#pragma unroll
    for (int j = 0; j < 8; ++j) r[j] = (__bf16)acc[j];
    ((bf16x8*)V2)[(size_t)b * 65536 + n8 * 128 + c] = r;
}

// fully-MFMA flash attention: QK^T (K=32, zero-padded) + PV both on matrix cores.
// block = (b, 16 queries); 4 waves; wave w owns m-cols [w*64, w*64+64) of each tile.
__global__ __launch_bounds__(256) void z_attn4(
    const float* __restrict__ q, const __bf16* __restrict__ kT, const __bf16* __restrict__ V2,
    const float* __restrict__ a, const float* __restrict__ gamp, float* __restrict__ attn)
{
    __shared__ __align__(16) unsigned char smem[8704];   // p_lds (8448B) / o_lds (8704B)
    __shared__ float wmax[4][16], wsum[4][16], fs[16];
    __bf16* p_lds = (__bf16*)smem;
    float* o_lds = (float*)smem;

    int tid = threadIdx.x;
    int b = blockIdx.x >> 8;
    int q0 = (blockIdx.x & 255) * QT;
    int l = tid & 63;
    int w = tid >> 6;
    int lm = l & 15;
    int g = l >> 4;

    // Q B-fragment: qfrag[j] = Q[c = g*8+j][q0+lm], zero for c>=16
    bf16x8 qfrag;
#pragma unroll
    for (int j = 0; j < 8; ++j) qfrag[j] = (__bf16)0.f;
    if (g < 2) {
#pragma unroll
        for (int j = 0; j < 8; ++j)
            qfrag[j] = (__bf16)q[((size_t)b * CQ_ + g * 8 + j) * NPIX + q0 + lm];
    }

    float m_run = -1e30f, l_run = 0.f;
    f32x4 acc0 = {0.f, 0.f, 0.f, 0.f};
    f32x4 acc1 = {0.f, 0.f, 0.f, 0.f};
    int c0 = w * 32 + lm;
    int c1 = c0 + 16;
    const bf16x8* vbase = (const bf16x8*)V2 + (size_t)b * 65536;
    const __bf16* ktb = kT + (size_t)b * NPIX * CQ_;

    for (int t = 0; t < NPIX / MT; ++t) {
        int m0 = t * MT;
        // ---- QK^T via MFMA: 4 m-subtiles per wave ----
        f32x4 sfr[4];
#pragma unroll
        for (int ms = 0; ms < 4; ++ms) {
            bf16x8 kf;
#pragma unroll
            for (int j = 0; j < 8; ++j) kf[j] = (__bf16)0.f;
            if (g < 2)
                kf = *(const bf16x8*)&ktb[(size_t)(m0 + w * 64 + ms * 16 + lm) * CQ_ + g * 8];
            f32x4 zz = {0.f, 0.f, 0.f, 0.f};
            sfr[ms] = __builtin_amdgcn_mfma_f32_16x16x32_bf16(kf, qfrag, zz, 0, 0, 0);
        }
        // ---- row max (register + shuffle + cross-wave LDS) ----
        float pmax = -1e30f;
#pragma unroll
        for (int ms = 0; ms < 4; ++ms)
#pragma unroll
            for (int r = 0; r < 4; ++r) pmax = fmaxf(pmax, sfr[ms][r]);
        pmax = fmaxf(pmax, __shfl_xor(pmax, 16));
        pmax = fmaxf(pmax, __shfl_xor(pmax, 32));
        if (g == 0) wmax[w][lm] = pmax;
        __syncthreads();
        float tmax = fmaxf(fmaxf(wmax[0][lm], wmax[1][lm]), fmaxf(wmax[2][lm], wmax[3][lm]));
        float nm = fmaxf(m_run, tmax);
        float f = __expf(m_run - nm);
        m_run = nm;
        if (w == 0 && g == 0) fs[lm] = f;
        // ---- exp, pack bf16 P, partial sum ----
        float psum = 0.f;
#pragma unroll
        for (int ms = 0; ms < 4; ++ms) {
            float p0 = __expf(sfr[ms][0] - nm);
            float p1 = __expf(sfr[ms][1] - nm);
            float p2 = __expf(sfr[ms][2] - nm);
            float p3 = __expf(sfr[ms][3] - nm);
            psum += (p0 + p1) + (p2 + p3);
            bf16x4 pk;
            pk[0] = (__bf16)p0; pk[1] = (__bf16)p1; pk[2] = (__bf16)p2; pk[3] = (__bf16)p3;
            *(bf16x4*)&p_lds[lm * 264 + w * 64 + ms * 16 + g * 4] = pk;
        }
        psum += __shfl_xor(psum, 16);
        psum += __shfl_xor(psum, 32);
        if (g == 0) wsum[w][lm] = psum;
        __syncthreads();
        float tsum = (wsum[0][lm] + wsum[1][lm]) + (wsum[2][lm] + wsum[3][lm]);
        l_run = l_run * f + tsum;
        // ---- rescale + PV MFMA ----
        float f0 = fs[g * 4 + 0], f1 = fs[g * 4 + 1], f2 = fs[g * 4 + 2], f3 = fs[g * 4 + 3];
        acc0[0] *= f0; acc0[1] *= f1; acc0[2] *= f2; acc0[3] *= f3;
        acc1[0] *= f0; acc1[1] *= f1; acc1[2] *= f2; acc1[3] *= f3;
#pragma unroll
        for (int ks = 0; ks < 8; ++ks) {
            bf16x8 afrag = *(const bf16x8*)&p_lds[lm * 264 + ks * 32 + g * 8];
            int msv = (m0 >> 3) + ks * 4 + g;
            bf16x8 bf0 = vbase[msv * 128 + c0];
            bf16x8 bf1 = vbase[msv * 128 + c1];
            acc0 = __builtin_amdgcn_mfma_f32_16x16x32_bf16(afrag, bf0, acc0, 0, 0, 0);
            acc1 = __builtin_amdgcn_mfma_f32_16x16x32_bf16(afrag, bf1, acc1, 0, 0, 0);
        }
        __syncthreads();   // p_lds reused next tile
    }

    // ---- epilogue ----
#pragma unroll
    for (int r = 0; r < 4; ++r) {
        int qrow = g * 4 + r;
        o_lds[c0 * 17 + qrow] = acc0[r];
        o_lds[c1 * 17 + qrow] = acc1[r];
    }
    __syncthreads();
    float gam = gamp[0];
    int qi = tid & 15;
    float inv = 1.f / l_run;
#pragma unroll
    for (int j = 0; j < 8; ++j) {
        int cc = (tid >> 4) + 16 * j;
        size_t idx = ((size_t)b * CO_ + cc) * NPIX + q0 + qi;
        attn[idx] = gam * (o_lds[cc * 17 + qi] * inv) + a[idx];
    }
}

// fused gate + final (unchanged, validated)
__global__ __launch_bounds__(256) void z_fuseout(
    const float* __restrict__ local, const float* __restrict__ attn,
    const float* __restrict__ x,
    const float* __restrict__ Wg, const float* __restrict__ bg,
    const float* __restrict__ g3, const float* __restrict__ b3n,
    const float* __restrict__ m3, const float* __restrict__ v3,
    const float* __restrict__ Wf, const float* __restrict__ bfb,
    const float* __restrict__ g4, const float* __restrict__ b4,
    const float* __restrict__ m4, const float* __restrict__ v4,
    const float* __restrict__ Wr, const float* __restrict__ rsp,
    float* __restrict__ out)
{
    __shared__ float sl[128][32];
    __shared__ float sa[128][32];
    __shared__ float sf[128][32];
    __shared__ float sx[64][32];

    int tid = threadIdx.x;
    int b = blockIdx.x >> 7;
    int n0 = (blockIdx.x & 127) * 32;

    for (int l = tid; l < 1024; l += 256) {
        int c = l >> 3, j = l & 7;
        *(float4*)&sl[c][j * 4] = ((const float4*)(local + ((size_t)b * CO_ + c) * NPIX + n0))[j];
        *(float4*)&sa[c][j * 4] = ((const float4*)(attn  + ((size_t)b * CO_ + c) * NPIX + n0))[j];
    }
    for (int l = tid; l < 512; l += 256) {
        int c = l >> 3, j = l & 7;
        *(float4*)&sx[c][j * 4] = ((const float4*)(x + ((size_t)b * CI_ + c) * NPIX + n0))[j];
    }
    __syncthreads();

    int co0 = (tid >> 3) * 4;
    int nn = (tid & 7) * 4;

    {
        float4 acc[4];
#pragma unroll
        for (int cc = 0; cc < 4; ++cc) {
            float bv = bg[co0 + cc];
            acc[cc].x = bv; acc[cc].y = bv; acc[cc].z = bv; acc[cc].w = bv;
        }
#pragma unroll 4
        for (int k = 0; k < 128; ++k) {
            float4 av = *(float4*)&sl[k][nn];
#pragma unroll
            for (int cc = 0; cc < 4; ++cc) {
                float w = Wg[(size_t)(co0 + cc) * 256 + k];
                acc[cc].x += w * av.x; acc[cc].y += w * av.y; acc[cc].z += w * av.z; acc[cc].w += w * av.w;
            }
        }
#pragma unroll 4
        for (int k = 0; k < 128; ++k) {
            float4 av = *(float4*)&sa[k][nn];
#pragma unroll
            for (int cc = 0; cc < 4; ++cc) {
                float w = Wg[(size_t)(co0 + cc) * 256 + 128 + k];
                acc[cc].x += w * av.x; acc[cc].y += w * av.y; acc[cc].z += w * av.z; acc[cc].w += w * av.w;
            }
        }
#pragma unroll
        for (int cc = 0; cc < 4; ++cc) {
            int co = co0 + cc;
            float sc = rsqrtf(v3[co] + EPS_) * g3[co];
            float sh = b3n[co] - m3[co] * sc;
            float4 lv = *(float4*)&sl[co][nn];
            float4 av = *(float4*)&sa[co][nn];
            float4 r;
            float gx = 1.f / (1.f + __expf(-(acc[cc].x * sc + sh)));
            float gy = 1.f / (1.f + __expf(-(acc[cc].y * sc + sh)));
            float gz = 1.f / (1.f + __expf(-(acc[cc].z * sc + sh)));
            float gw = 1.f / (1.f + __expf(-(acc[cc].w * sc + sh)));
            r.x = gx * lv.x + (1.f - gx) * av.x;
            r.y = gy * lv.y + (1.f - gy) * av.y;
            r.z = gz * lv.z + (1.f - gz) * av.z;
            r.w = gw * lv.w + (1.f - gw) * av.w;
            *(float4*)&sf[co][nn] = r;
        }
    }
    __syncthreads();

    {
        float4 acc[4];
#pragma unroll
        for (int cc = 0; cc < 4; ++cc) {
            float bv = bfb[co0 + cc];
            acc[cc].x = bv; acc[cc].y = bv; acc[cc].z = bv; acc[cc].w = bv;
        }
#pragma unroll 4
        for (int k = 0; k < 128; ++k) {
            float4 av = *(float4*)&sf[k][nn];
#pragma unroll
            for (int cc = 0; cc < 4; ++cc) {
                float w = Wf[(size_t)(co0 + cc) * 384 + k];
                acc[cc].x += w * av.x; acc[cc].y += w * av.y; acc[cc].z += w * av.z; acc[cc].w += w * av.w;
            }
        }
#pragma unroll 4
        for (int k = 0; k < 128; ++k) {
            float4 av = *(float4*)&sl[k][nn];
#pragma unroll
            for (int cc = 0; cc < 4; ++cc) {
                float w = Wf[(size_t)(co0 + cc) * 384 + 128 + k];
                acc[cc].x += w * av.x; acc[cc].y += w * av.y; acc[cc].z += w * av.z; acc[cc].w += w * av.w;
            }
        }
#pragma unroll 4
        for (int k = 0; k < 128; ++k) {
            float4 av = *(float4*)&sa[k][nn];
#pragma unroll
            for (int cc = 0; cc < 4; ++cc) {
                float w = Wf[(size_t)(co0 + cc) * 384 + 256 + k];
                acc[cc].x += w * av.x; acc[cc].y += w * av.y; acc[cc].z += w * av.z; acc[cc].w += w * av.w;
            }
        }
        float4 rr[4];
#pragma unroll
        for (int cc = 0; cc < 4; ++cc) { rr[cc].x = 0.f; rr[cc].y = 0.f; rr[cc].z = 0.f; rr[cc].w = 0.f; }
#pragma unroll 4
        for (int k = 0; k < 64; ++k) {
            float4 av = *(float4*)&sx[k][nn];
#pragma unroll
            for (int cc = 0; cc < 4; ++cc) {
                float w = Wr[(size_t)(co0 + cc) * 64 + k];
                rr[cc].x += w * av.x; rr[cc].y += w * av.y; rr[cc].z += w * av.z; rr[cc].w += w * av.w;
            }
        }
        float rsv = rsp[0];
#pragma unroll
        for (int cc = 0; cc < 4; ++cc) {
            int co = co0 + cc;
            float sc = rsqrtf(v4[co] + EPS_) * g4[co];
            float sh = b4[co] - m4[co] * sc;
            float4 r;
            r.x = fmaxf(acc[cc].x * sc + sh, 0.f) + rsv * rr[cc].x;
            r.y = fmaxf(acc[cc].y * sc + sh, 0.f) + rsv * rr[cc].y;
            r.z = fmaxf(acc[cc].z * sc + sh, 0.f) + rsv * rr[cc].z;
            r.w = fmaxf(acc[cc].w * sc + sh, 0.f) + rsv * rr[cc].w;
            *(float4*)(out + ((size_t)b * CO_ + co) * NPIX + n0 + nn) = r;
        }
    }
}

extern "C" void kernel_launch(void* const* d_in, const int* in_sizes, int n_in,
                              void* d_out, int out_size, void* d_ws, size_t ws_size,
                              hipStream_t stream) {
    const float* x   = (const float*)d_in[0];
    const float* W3  = (const float*)d_in[1];
    const float* b3  = (const float*)d_in[2];
    const float* g1  = (const float*)d_in[3];
    const float* b1  = (const float*)d_in[4];
    const float* m1  = (const float*)d_in[5];
    const float* v1  = (const float*)d_in[6];
    const float* Wa  = (const float*)d_in[7];
    const float* ba  = (const float*)d_in[8];
    const float* g2  = (const float*)d_in[9];
    const float* b2  = (const float*)d_in[10];
    const float* m2  = (const float*)d_in[11];
    const float* v2  = (const float*)d_in[12];
    const float* Wq  = (const float*)d_in[13];
    const float* bq  = (const float*)d_in[14];
    const float* Wk  = (const float*)d_in[15];
    const float* bk  = (const float*)d_in[16];
    const float* Wv  = (const float*)d_in[17];
    const float* bv  = (const float*)d_in[18];
    const float* gam = (const float*)d_in[19];
    const float* Wg  = (const float*)d_in[20];
    const float* bg  = (const float*)d_in[21];
    const float* g3  = (const float*)d_in[22];
    const float* b3n = (const float*)d_in[23];
    const float* m3  = (const float*)d_in[24];
    const float* v3  = (const float*)d_in[25];
    const float* Wf  = (const float*)d_in[26];
    const float* bfb = (const float*)d_in[27];
    const float* g4  = (const float*)d_in[28];
    const float* b4  = (const float*)d_in[29];
    const float* m4  = (const float*)d_in[30];
    const float* v4  = (const float*)d_in[31];
    const float* Wr  = (const float*)d_in[32];
    const float* rs  = (const float*)d_in[33];

    float* ws    = (float*)d_ws;
    float* a_    = ws;                       // [0, 2M)
    float* local = ws + 2097152;             // [2M, 4M)
    float* attn  = ws + 4194304;             // [4M, 6M)
    __bf16* V2   = (__bf16*)(ws + 6291456);  // 4 MB bf16
    float* q     = ws + 7340032;             // 262,144 floats
    __bf16* kT   = (__bf16*)(ws + 7602176);  // 512 KB bf16 (4*4096*16)
    __bf16* xT   = (__bf16*)(ws + 7864320);  // 2 MB bf16
    __bf16* Wt2  = (__bf16*)(ws + 8388608);  // 147 KB bf16

    float* out = (float*)d_out;

    z_prepx<<<256, 256, 0, stream>>>(x, xT);
    z_prepw<<<288, 256, 0, stream>>>(W3, Wt2);
    z_proj_a4<<<2048, 256, 0, stream>>>(x, Wa, ba, g2, b2, m2, v2, a_);
    z_projqk<<<1024, 256, 0, stream>>>(a_, Wq, bq, q);
    z_projkT<<<1024, 256, 0, stream>>>(a_, Wk, bk, kT);
    z_projv2<<<1024, 256, 0, stream>>>(a_, Wv, bv, V2);
    z_attn4<<<1024, 256, 0, stream>>>(q, kT, V2, a_, gam, attn);
    z_conv3m<<<1024, 256, 0, stream>>>(xT, Wt2, b3, g1, b1, m1, v1, local);
    z_fuseout<<<512, 256, 0, stream>>>(local, attn, x, Wg, bg, g3, b3n, m3, v3,
                                       Wf, bfb, g4, b4, m4, v4, Wr, rs, out);
}